// Round 1
// baseline (1585.665 us; speedup 1.0000x reference)
//
#include <hip/hip_runtime.h>
#include <math.h>

#define BB 64
#define T 128
#define DD 768
#define H 256
#define JJ 128
#define NSPAN 8256
#define KTOP 256

// ---------------------------------------------------------------------------
// Kernel 0: build triu span index tables (start-major, matches jnp.triu_indices)
// ---------------------------------------------------------------------------
__global__ void build_idx_kernel(int* s_idx, int* e_idx) {
    int s = threadIdx.x;
    if (s < T) {
        int start = s * T - (s * (s - 1)) / 2;
        int len = T - s;
        for (int i = 0; i < len; ++i) {
            s_idx[start + i] = s;
            e_idx[start + i] = s + i;
        }
    }
}

// ---------------------------------------------------------------------------
// Kernel 1: proj GEMM. AE[m][0:256] = X@W_start + b_start ; AE[m][256:512] = X@W_end + b_end
// X = inputs [8192][768]. Tile 64 rows x 128 cols, KC=16, micro 8x4.
// ---------------------------------------------------------------------------
__global__ __launch_bounds__(256) void proj_kernel(
    const float* __restrict__ X,
    const float* __restrict__ Wa, const float* __restrict__ ba,
    const float* __restrict__ Wb, const float* __restrict__ bb,
    float* __restrict__ AE)
{
    const int m0 = blockIdx.x * 64;
    const int c0 = blockIdx.y * 128;     // global output col (0..511)
    const float* W;
    const float* bias;
    int wc0;
    if (c0 < 256) { W = Wa; bias = ba; wc0 = c0; }
    else          { W = Wb; bias = bb; wc0 = c0 - 256; }

    __shared__ float Xs[64][20];   // 16 k + pad
    __shared__ float Ws[16][132];  // 128 cols + pad

    const int t  = threadIdx.x;
    const int tx = t & 31;   // 32 col groups of 4
    const int ty = t >> 5;   // 8 row groups of 8

    float acc[8][4];
#pragma unroll
    for (int i = 0; i < 8; ++i)
#pragma unroll
        for (int j = 0; j < 4; ++j) acc[i][j] = 0.f;

    for (int kk = 0; kk < DD; kk += 16) {
        __syncthreads();
        {   // X tile 64x16
            int row = t >> 2, k4 = (t & 3) * 4;
            float4 v = *(const float4*)&X[(size_t)(m0 + row) * DD + kk + k4];
            *(float4*)&Xs[row][k4] = v;
        }
        {   // W tile 16x128
            int row = t >> 4, c8 = (t & 15) * 8;
            float4 w0 = *(const float4*)&W[(size_t)(kk + row) * 256 + wc0 + c8];
            float4 w1 = *(const float4*)&W[(size_t)(kk + row) * 256 + wc0 + c8 + 4];
            *(float4*)&Ws[row][c8]     = w0;
            *(float4*)&Ws[row][c8 + 4] = w1;
        }
        __syncthreads();
#pragma unroll
        for (int k4 = 0; k4 < 16; k4 += 4) {
            float w[4][4];
#pragma unroll
            for (int kq = 0; kq < 4; ++kq) {
                float4 wv = *(const float4*)&Ws[k4 + kq][tx * 4];
                w[kq][0] = wv.x; w[kq][1] = wv.y; w[kq][2] = wv.z; w[kq][3] = wv.w;
            }
#pragma unroll
            for (int i = 0; i < 8; ++i) {
                float4 xv = *(const float4*)&Xs[ty * 8 + i][k4];
                float xq[4] = {xv.x, xv.y, xv.z, xv.w};
#pragma unroll
                for (int kq = 0; kq < 4; ++kq)
#pragma unroll
                    for (int j = 0; j < 4; ++j)
                        acc[i][j] = fmaf(xq[kq], w[kq][j], acc[i][j]);
            }
        }
    }
    float bj[4];
#pragma unroll
    for (int j = 0; j < 4; ++j) bj[j] = bias[wc0 + tx * 4 + j];
#pragma unroll
    for (int i = 0; i < 8; ++i) {
        float4 o;
        o.x = acc[i][0] + bj[0]; o.y = acc[i][1] + bj[1];
        o.z = acc[i][2] + bj[2]; o.w = acc[i][3] + bj[3];
        *(float4*)&AE[(size_t)(m0 + ty * 8 + i) * 512 + c0 + tx * 4] = o;
    }
}

// ---------------------------------------------------------------------------
// Kernel 2: span scorer. Per block: 128 spans x 256 cols, K=256 (KC=32).
// score[n] = relu( relu(sh) @ W_s1 + b_s1 ) . W_s2 + b_s2, masked to -inf.
// ---------------------------------------------------------------------------
__global__ __launch_bounds__(256) void score_kernel(
    const float* __restrict__ AE,
    const float* __restrict__ Ws1, const float* __restrict__ bs1,
    const float* __restrict__ Ws2, const float* __restrict__ bs2g,
    const int* __restrict__ s_idx, const int* __restrict__ e_idx,
    const int* __restrict__ maskp,
    float* __restrict__ scores)
{
    const int b  = blockIdx.y;
    const int n0 = blockIdx.x * 128;

    __shared__ float rsh[128][36];
    __shared__ float Ws[32][260];
    __shared__ int   ss[128], se[128];
    __shared__ float msk[128];

    const int t = threadIdx.x;
    if (t < 128) {
        int n = n0 + t;
        int s = 0, e = 0;
        float mv = 0.f;
        if (n < NSPAN) {
            s = s_idx[n]; e = e_idx[n];
            mv = (maskp[b * T + s] != 0 && maskp[b * T + e] != 0) ? 1.f : 0.f;
        }
        ss[t] = s; se[t] = e; msk[t] = mv;
    }
    __syncthreads();

    const int tx = t & 31;   // 32 col groups of 8
    const int ty = t >> 5;   // 8 row groups of 16
    float acc[16][8];
#pragma unroll
    for (int i = 0; i < 16; ++i)
#pragma unroll
        for (int j = 0; j < 8; ++j) acc[i][j] = 0.f;

    const float* Abase = AE + (size_t)b * T * 512;

    for (int kk = 0; kk < 256; kk += 32) {
        __syncthreads();
        {   // W_s1 chunk 32 x 256
            int c4 = (t & 63) * 4, r0 = t >> 6;
#pragma unroll
            for (int r8 = 0; r8 < 8; ++r8) {
                int row = r0 + r8 * 4;
                *(float4*)&Ws[row][c4] =
                    *(const float4*)&Ws1[(size_t)(kk + row) * 256 + c4];
            }
        }
        {   // rsh chunk: relu(A[s] + E[e]) 128 x 32
            int sp = t >> 1, k16 = (t & 1) * 16;
            const float* Ar = Abase + (size_t)ss[sp] * 512 + kk + k16;
            const float* Er = Abase + (size_t)se[sp] * 512 + 256 + kk + k16;
#pragma unroll
            for (int q = 0; q < 4; ++q) {
                float4 a = *(const float4*)&Ar[q * 4];
                float4 e = *(const float4*)&Er[q * 4];
                float4 v;
                v.x = fmaxf(a.x + e.x, 0.f); v.y = fmaxf(a.y + e.y, 0.f);
                v.z = fmaxf(a.z + e.z, 0.f); v.w = fmaxf(a.w + e.w, 0.f);
                *(float4*)&rsh[sp][k16 + q * 4] = v;
            }
        }
        __syncthreads();
#pragma unroll
        for (int k4 = 0; k4 < 32; k4 += 4) {
            float w[4][8];
#pragma unroll
            for (int kq = 0; kq < 4; ++kq) {
                float4 w0 = *(const float4*)&Ws[k4 + kq][tx * 8];
                float4 w1 = *(const float4*)&Ws[k4 + kq][tx * 8 + 4];
                w[kq][0] = w0.x; w[kq][1] = w0.y; w[kq][2] = w0.z; w[kq][3] = w0.w;
                w[kq][4] = w1.x; w[kq][5] = w1.y; w[kq][6] = w1.z; w[kq][7] = w1.w;
            }
#pragma unroll
            for (int i = 0; i < 16; ++i) {
                float4 rv = *(const float4*)&rsh[ty * 16 + i][k4];
                float rq[4] = {rv.x, rv.y, rv.z, rv.w};
#pragma unroll
                for (int kq = 0; kq < 4; ++kq)
#pragma unroll
                    for (int j = 0; j < 8; ++j)
                        acc[i][j] = fmaf(rq[kq], w[kq][j], acc[i][j]);
            }
        }
    }

    // epilogue: relu(h + b_s1) . W_s2, reduce over tx (32 lanes), mask, store
    float b1[8], w2[8];
#pragma unroll
    for (int j = 0; j < 8; ++j) {
        int c = tx * 8 + j;
        b1[j] = bs1[c];
        w2[j] = Ws2[c];
    }
    const float bs2v = bs2g[0];
#pragma unroll
    for (int i = 0; i < 16; ++i) {
        int r = ty * 16 + i;
        float p = 0.f;
#pragma unroll
        for (int j = 0; j < 8; ++j)
            p += fmaxf(acc[i][j] + b1[j], 0.f) * w2[j];
#pragma unroll
        for (int off = 16; off > 0; off >>= 1)
            p += __shfl_down(p, off, 32);
        if (tx == 0) {
            int n = n0 + r;
            if (n < NSPAN) {
                float sc = p + bs2v;
                scores[(size_t)b * NSPAN + n] = (msk[r] > 0.f) ? sc : -INFINITY;
            }
        }
    }
}

// ---------------------------------------------------------------------------
// Kernel 3: injection projection. inj[b][h] = tie[b]@W_inj + b_inj
// ---------------------------------------------------------------------------
__global__ __launch_bounds__(256) void inj_kernel(
    const float* __restrict__ tie, const float* __restrict__ Winj,
    const float* __restrict__ binj, float* __restrict__ inj)
{
    int b = blockIdx.x;
    int h = threadIdx.x;
    __shared__ float tb[JJ];
    if (threadIdx.x < JJ) tb[threadIdx.x] = tie[b * JJ + threadIdx.x];
    __syncthreads();
    float a = binj[h];
    for (int j = 0; j < JJ; ++j)
        a = fmaf(tb[j], Winj[j * H + h], a);
    inj[b * H + h] = a;
}

// ---------------------------------------------------------------------------
// Kernel 4: per-batch top-K (K=256 of N=8256), jax tie-break (lowest index),
// output indices ascending (matches jnp.sort(top_idx)).
// ---------------------------------------------------------------------------
__global__ __launch_bounds__(256) void topk_kernel(
    const float* __restrict__ scores,
    int* __restrict__ top_idx, float* __restrict__ top_scores)
{
    const int b = blockIdx.x;
    const int t = threadIdx.x;
    __shared__ unsigned su[NSPAN];
    __shared__ int red[4];
    __shared__ int wave_eq[4], wave_keep[4];

    const float* sc = scores + (size_t)b * NSPAN;
    for (int i = t; i < NSPAN; i += 256) {
        unsigned ub = __float_as_uint(sc[i]);
        su[i] = (ub & 0x80000000u) ? ~ub : (ub | 0x80000000u);
    }
    __syncthreads();

    // radix-select the K-th largest key
    unsigned prefix = 0;
    int remaining = KTOP;
    const int wid = t >> 6, lane = t & 63;
    for (int bit = 31; bit >= 0; --bit) {
        unsigned pat = (prefix >> bit) | 1u;
        int cnt = 0;
        for (int i = t; i < NSPAN; i += 256)
            cnt += ((su[i] >> bit) == pat) ? 1 : 0;
#pragma unroll
        for (int off = 32; off > 0; off >>= 1)
            cnt += __shfl_down(cnt, off, 64);
        if (lane == 0) red[wid] = cnt;
        __syncthreads();
        int c = red[0] + red[1] + red[2] + red[3];
        if (c >= remaining) prefix |= (1u << bit);
        else remaining -= c;
        __syncthreads();
    }
    const unsigned v = prefix;
    const int need_eq = remaining;

    // emit in index order: all u>v, plus first need_eq with u==v
    int base_eq = 0, base_keep = 0;
    const unsigned long long ltmask = (1ull << lane) - 1ull;
    for (int c0 = 0; c0 < NSPAN; c0 += 256) {
        int n = c0 + t;
        bool valid = n < NSPAN;
        unsigned u = valid ? su[n] : 0u;
        bool eq = valid && (u == v);
        bool gt = valid && (u > v);
        unsigned long long beq = __ballot(eq);
        int eq_before = __popcll(beq & ltmask);
        if (lane == 0) wave_eq[wid] = __popcll(beq);
        __syncthreads();
        int eqb = base_eq;
        for (int w = 0; w < wid; ++w) eqb += wave_eq[w];
        int eq_rank = eqb + eq_before;
        bool keep = gt || (eq && (eq_rank < need_eq));
        unsigned long long bk = __ballot(keep);
        int keep_before = __popcll(bk & ltmask);
        if (lane == 0) wave_keep[wid] = __popcll(bk);
        __syncthreads();
        int kb = base_keep;
        for (int w = 0; w < wid; ++w) kb += wave_keep[w];
        if (keep) {
            int pos = kb + keep_before;
            top_idx[b * KTOP + pos] = n;
            unsigned fb = (u & 0x80000000u) ? (u & 0x7FFFFFFFu) : ~u;
            float f = __uint_as_float(fb);
            top_scores[b * KTOP + pos] = isinf(f) ? -1.0f : f;
        }
        for (int w = 0; w < 4; ++w) { base_eq += wave_eq[w]; base_keep += wave_keep[w]; }
        __syncthreads();
    }
}

// ---------------------------------------------------------------------------
// Kernel 5: final head. 64 gathered spans per block x 256 cols, K=256.
// out = sigmoid( relu(inj + sh@W_sec + b_sec) . W_pred + b_pred + top_score ) * mask
// ---------------------------------------------------------------------------
__global__ __launch_bounds__(256) void final_kernel(
    const float* __restrict__ AE,
    const int* __restrict__ s_idx, const int* __restrict__ e_idx,
    const int* __restrict__ maskp,
    const int* __restrict__ top_idx, const float* __restrict__ top_scores,
    const float* __restrict__ injv,
    const float* __restrict__ Wsec, const float* __restrict__ bsec,
    const float* __restrict__ Wpred, const float* __restrict__ bpredg,
    float* __restrict__ out)
{
    const int b = blockIdx.x >> 2;
    const int k0 = (blockIdx.x & 3) * 64;

    __shared__ float sh[64][36];
    __shared__ float Ws[32][260];
    __shared__ int ss[64], se[64];
    __shared__ float msk[64], tsc[64];

    const int t = threadIdx.x;
    if (t < 64) {
        int kidx = k0 + t;
        int n = top_idx[b * KTOP + kidx];
        int s = s_idx[n], e = e_idx[n];
        ss[t] = s; se[t] = e;
        msk[t] = (maskp[b * T + s] != 0 && maskp[b * T + e] != 0) ? 1.f : 0.f;
        tsc[t] = top_scores[b * KTOP + kidx];
    }
    __syncthreads();

    const int tx = t & 31;   // 32 col groups of 8
    const int ty = t >> 5;   // 8 row groups of 8
    float acc[8][8];
#pragma unroll
    for (int i = 0; i < 8; ++i)
#pragma unroll
        for (int j = 0; j < 8; ++j) acc[i][j] = 0.f;

    const float* Abase = AE + (size_t)b * T * 512;

    for (int kk = 0; kk < 256; kk += 32) {
        __syncthreads();
        {   // W_sec chunk 32 x 256
            int c4 = (t & 63) * 4, r0 = t >> 6;
#pragma unroll
            for (int r8 = 0; r8 < 8; ++r8) {
                int row = r0 + r8 * 4;
                *(float4*)&Ws[row][c4] =
                    *(const float4*)&Wsec[(size_t)(kk + row) * 256 + c4];
            }
        }
        {   // sh chunk: A[s] + E[e] (no relu) 64 x 32
            int sp = t >> 2, k8 = (t & 3) * 8;
            const float* Ar = Abase + (size_t)ss[sp] * 512 + kk + k8;
            const float* Er = Abase + (size_t)se[sp] * 512 + 256 + kk + k8;
#pragma unroll
            for (int q = 0; q < 2; ++q) {
                float4 a = *(const float4*)&Ar[q * 4];
                float4 e = *(const float4*)&Er[q * 4];
                float4 v;
                v.x = a.x + e.x; v.y = a.y + e.y; v.z = a.z + e.z; v.w = a.w + e.w;
                *(float4*)&sh[sp][k8 + q * 4] = v;
            }
        }
        __syncthreads();
#pragma unroll
        for (int k4 = 0; k4 < 32; k4 += 4) {
            float w[4][8];
#pragma unroll
            for (int kq = 0; kq < 4; ++kq) {
                float4 w0 = *(const float4*)&Ws[k4 + kq][tx * 8];
                float4 w1 = *(const float4*)&Ws[k4 + kq][tx * 8 + 4];
                w[kq][0] = w0.x; w[kq][1] = w0.y; w[kq][2] = w0.z; w[kq][3] = w0.w;
                w[kq][4] = w1.x; w[kq][5] = w1.y; w[kq][6] = w1.z; w[kq][7] = w1.w;
            }
#pragma unroll
            for (int i = 0; i < 8; ++i) {
                float4 rv = *(const float4*)&sh[ty * 8 + i][k4];
                float rq[4] = {rv.x, rv.y, rv.z, rv.w};
#pragma unroll
                for (int kq = 0; kq < 4; ++kq)
#pragma unroll
                    for (int j = 0; j < 8; ++j)
                        acc[i][j] = fmaf(rq[kq], w[kq][j], acc[i][j]);
            }
        }
    }

    float bsec_r[8], wpred_r[8], injr[8];
#pragma unroll
    for (int j = 0; j < 8; ++j) {
        int c = tx * 8 + j;
        bsec_r[j] = bsec[c];
        wpred_r[j] = Wpred[c];
        injr[j] = injv[b * H + c];
    }
    const float bp = bpredg[0];
#pragma unroll
    for (int i = 0; i < 8; ++i) {
        int r = ty * 8 + i;
        float p = 0.f;
#pragma unroll
        for (int j = 0; j < 8; ++j) {
            float sec = acc[i][j] + bsec_r[j];
            p += fmaxf(injr[j] + sec, 0.f) * wpred_r[j];
        }
#pragma unroll
        for (int off = 16; off > 0; off >>= 1)
            p += __shfl_down(p, off, 32);
        if (tx == 0) {
            float logit = p + bp + tsc[r];
            float prob = (1.f / (1.f + expf(-logit))) * msk[r];
            out[b * KTOP + k0 + r] = prob;
        }
    }
}

// ---------------------------------------------------------------------------
extern "C" void kernel_launch(void* const* d_in, const int* in_sizes, int n_in,
                              void* d_out, int out_size, void* d_ws, size_t ws_size,
                              hipStream_t stream) {
    const float* inputs  = (const float*)d_in[0];
    const int*   imask   = (const int*)d_in[1];
    const float* tie     = (const float*)d_in[2];
    const float* W_start = (const float*)d_in[3];
    const float* b_start = (const float*)d_in[4];
    const float* W_end   = (const float*)d_in[5];
    const float* b_end   = (const float*)d_in[6];
    const float* W_s1    = (const float*)d_in[7];
    const float* b_s1    = (const float*)d_in[8];
    const float* W_s2    = (const float*)d_in[9];
    const float* b_s2    = (const float*)d_in[10];
    const float* W_inj   = (const float*)d_in[11];
    const float* b_inj   = (const float*)d_in[12];
    const float* W_sec   = (const float*)d_in[13];
    const float* b_sec   = (const float*)d_in[14];
    const float* W_pred  = (const float*)d_in[15];
    const float* b_pred  = (const float*)d_in[16];
    float* out = (float*)d_out;

    // workspace layout (floats): AE | scores | s_idx | e_idx | top_idx | top_scores | inj
    float* AE         = (float*)d_ws;
    float* scores     = AE + (size_t)BB * T * 512;           // 4,194,304
    int*   s_idx      = (int*)(scores + (size_t)BB * NSPAN); // +528,384
    int*   e_idx      = s_idx + NSPAN;
    int*   top_idx    = e_idx + NSPAN;
    float* top_scores = (float*)(top_idx + BB * KTOP);
    float* injv       = top_scores + BB * KTOP;

    build_idx_kernel<<<1, 128, 0, stream>>>(s_idx, e_idx);
    proj_kernel<<<dim3(128, 4), 256, 0, stream>>>(inputs, W_start, b_start, W_end, b_end, AE);
    score_kernel<<<dim3(65, BB), 256, 0, stream>>>(AE, W_s1, b_s1, W_s2, b_s2,
                                                   s_idx, e_idx, imask, scores);
    inj_kernel<<<BB, 256, 0, stream>>>(tie, W_inj, b_inj, injv);
    topk_kernel<<<BB, 256, 0, stream>>>(scores, top_idx, top_scores);
    final_kernel<<<BB * 4, 256, 0, stream>>>(AE, s_idx, e_idx, imask, top_idx, top_scores,
                                             injv, W_sec, b_sec, W_pred, b_pred, out);
}

// Round 2
// 643.815 us; speedup vs baseline: 2.4629x; 2.4629x over previous
//
#include <hip/hip_runtime.h>
#include <math.h>

#define BB 64
#define T 128
#define DD 768
#define H 256
#define JJ 128
#define NSPAN 8256
#define KTOP 256
#define SCAP 1024
#define MARGIN 0.03f

typedef __attribute__((ext_vector_type(8))) short bf16x8;
typedef __attribute__((ext_vector_type(4))) float f32x4;
typedef __attribute__((ext_vector_type(8))) unsigned short us8;

__device__ inline unsigned short bfrne(float x) {
    unsigned u = __float_as_uint(x);
    return (unsigned short)((u + 0x7FFFu + ((u >> 16) & 1u)) >> 16);
}

// ---------------------------------------------------------------------------
// Kernel 0: build triu span index tables (start-major, matches jnp.triu_indices)
// ---------------------------------------------------------------------------
__global__ void build_idx_kernel(int* s_idx, int* e_idx) {
    int s = threadIdx.x;
    if (s < T) {
        int start = s * T - (s * (s - 1)) / 2;
        int len = T - s;
        for (int i = 0; i < len; ++i) {
            s_idx[start + i] = s;
            e_idx[start + i] = s + i;
        }
    }
}

// ---------------------------------------------------------------------------
// Kernel 1: proj GEMM. AE[m][0:256] = X@W_start + b_start ; AE[m][256:512] = X@W_end + b_end
// ---------------------------------------------------------------------------
__global__ __launch_bounds__(256) void proj_kernel(
    const float* __restrict__ X,
    const float* __restrict__ Wa, const float* __restrict__ ba,
    const float* __restrict__ Wb, const float* __restrict__ bb,
    float* __restrict__ AE)
{
    const int m0 = blockIdx.x * 64;
    const int c0 = blockIdx.y * 128;
    const float* W;
    const float* bias;
    int wc0;
    if (c0 < 256) { W = Wa; bias = ba; wc0 = c0; }
    else          { W = Wb; bias = bb; wc0 = c0 - 256; }

    __shared__ float Xs[64][20];
    __shared__ float Ws[16][132];

    const int t  = threadIdx.x;
    const int tx = t & 31;
    const int ty = t >> 5;

    float acc[8][4];
#pragma unroll
    for (int i = 0; i < 8; ++i)
#pragma unroll
        for (int j = 0; j < 4; ++j) acc[i][j] = 0.f;

    for (int kk = 0; kk < DD; kk += 16) {
        __syncthreads();
        {
            int row = t >> 2, k4 = (t & 3) * 4;
            float4 v = *(const float4*)&X[(size_t)(m0 + row) * DD + kk + k4];
            *(float4*)&Xs[row][k4] = v;
        }
        {
            int row = t >> 4, c8 = (t & 15) * 8;
            float4 w0 = *(const float4*)&W[(size_t)(kk + row) * 256 + wc0 + c8];
            float4 w1 = *(const float4*)&W[(size_t)(kk + row) * 256 + wc0 + c8 + 4];
            *(float4*)&Ws[row][c8]     = w0;
            *(float4*)&Ws[row][c8 + 4] = w1;
        }
        __syncthreads();
#pragma unroll
        for (int k4 = 0; k4 < 16; k4 += 4) {
            float w[4][4];
#pragma unroll
            for (int kq = 0; kq < 4; ++kq) {
                float4 wv = *(const float4*)&Ws[k4 + kq][tx * 4];
                w[kq][0] = wv.x; w[kq][1] = wv.y; w[kq][2] = wv.z; w[kq][3] = wv.w;
            }
#pragma unroll
            for (int i = 0; i < 8; ++i) {
                float4 xv = *(const float4*)&Xs[ty * 8 + i][k4];
                float xq[4] = {xv.x, xv.y, xv.z, xv.w};
#pragma unroll
                for (int kq = 0; kq < 4; ++kq)
#pragma unroll
                    for (int j = 0; j < 4; ++j)
                        acc[i][j] = fmaf(xq[kq], w[kq][j], acc[i][j]);
            }
        }
    }
    float bj[4];
#pragma unroll
    for (int j = 0; j < 4; ++j) bj[j] = bias[wc0 + tx * 4 + j];
#pragma unroll
    for (int i = 0; i < 8; ++i) {
        float4 o;
        o.x = acc[i][0] + bj[0]; o.y = acc[i][1] + bj[1];
        o.z = acc[i][2] + bj[2]; o.w = acc[i][3] + bj[3];
        *(float4*)&AE[(size_t)(m0 + ty * 8 + i) * 512 + c0 + tx * 4] = o;
    }
}

// ---------------------------------------------------------------------------
// Kernel 1b: pack W_s1 into bf16 MFMA B-fragment layout.
// Frag (ct, kc): lane l, elem j  <-  W1[k = kc*32 + (l>>4)*8 + j][n = ct*16 + (l&15)]
// ---------------------------------------------------------------------------
__global__ __launch_bounds__(256) void wpack_kernel(
    const float* __restrict__ W1, unsigned short* __restrict__ Wpk)
{
    int idx = blockIdx.x * 256 + threadIdx.x;   // 65536 total
    int j  = idx & 7;
    int l  = (idx >> 3) & 63;
    int kc = (idx >> 9) & 7;
    int ct = idx >> 12;
    int k = kc * 32 + (l >> 4) * 8 + j;
    int n = ct * 16 + (l & 15);
    Wpk[idx] = bfrne(W1[k * 256 + n]);
}

// ---------------------------------------------------------------------------
// Kernel 2: approximate span scorer via bf16 MFMA 16x16x32.
// Block: 128 spans, full N=256, K=256. A staged bf16 in LDS once -> registers.
// B fragments streamed from pre-packed global (L1/L2 resident).
// Layer-2 folded in-register; writes approx scores (masked -> -inf).
// ---------------------------------------------------------------------------
__global__ __launch_bounds__(256) void approx_kernel(
    const float* __restrict__ AE,
    const unsigned short* __restrict__ Wpk,
    const float* __restrict__ bs1, const float* __restrict__ Ws2,
    const float* __restrict__ bs2g,
    const int* __restrict__ s_idx, const int* __restrict__ e_idx,
    const int* __restrict__ maskp,
    float* __restrict__ scores)
{
    const int b  = blockIdx.y;
    const int n0 = blockIdx.x * 128;

    __shared__ unsigned short rsh[128][264];   // bf16, padded (264*2=528B pitch)
    __shared__ int   ss[128], se[128];
    __shared__ float msk[128];

    const int t = threadIdx.x;
    if (t < 128) {
        int n = n0 + t;
        int s = 0, e = 0;
        float mv = 0.f;
        if (n < NSPAN) {
            s = s_idx[n]; e = e_idx[n];
            mv = (maskp[b * T + s] != 0 && maskp[b * T + e] != 0) ? 1.f : 0.f;
        }
        ss[t] = s; se[t] = e; msk[t] = mv;
    }
    __syncthreads();

    const float* Abase = AE + (size_t)b * T * 512;
    {   // stage relu(A[s]+E[e]) as bf16: thread t handles span t>>1, k-half (t&1)*128
        int sp = t >> 1;
        int kbase = (t & 1) * 128;
        const float* Ar = Abase + (size_t)ss[sp] * 512 + kbase;
        const float* Er = Abase + (size_t)se[sp] * 512 + 256 + kbase;
        unsigned short* dst = &rsh[sp][kbase];
#pragma unroll
        for (int i = 0; i < 16; ++i) {
            float4 a0 = *(const float4*)&Ar[i * 8];
            float4 a1 = *(const float4*)&Ar[i * 8 + 4];
            float4 e0 = *(const float4*)&Er[i * 8];
            float4 e1 = *(const float4*)&Er[i * 8 + 4];
            us8 v;
            v[0] = bfrne(fmaxf(a0.x + e0.x, 0.f));
            v[1] = bfrne(fmaxf(a0.y + e0.y, 0.f));
            v[2] = bfrne(fmaxf(a0.z + e0.z, 0.f));
            v[3] = bfrne(fmaxf(a0.w + e0.w, 0.f));
            v[4] = bfrne(fmaxf(a1.x + e1.x, 0.f));
            v[5] = bfrne(fmaxf(a1.y + e1.y, 0.f));
            v[6] = bfrne(fmaxf(a1.z + e1.z, 0.f));
            v[7] = bfrne(fmaxf(a1.w + e1.w, 0.f));
            *(us8*)&dst[i * 8] = v;
        }
    }
    __syncthreads();

    const int w    = t >> 6;      // wave 0..3 -> spans [w*32, w*32+32)
    const int lane = t & 63;
    const int lrow = lane & 15;
    const int quad = lane >> 4;

    // A fragments for both 16-span tiles, all 8 K-chunks, into registers
    bf16x8 afr[2][8];
#pragma unroll
    for (int sp = 0; sp < 2; ++sp) {
        int row = w * 32 + sp * 16 + lrow;
#pragma unroll
        for (int kc = 0; kc < 8; ++kc)
            afr[sp][kc] = *(const bf16x8*)&rsh[row][kc * 32 + quad * 8];
    }

    float p[2][4] = {{0.f,0.f,0.f,0.f},{0.f,0.f,0.f,0.f}};
#pragma unroll
    for (int ct = 0; ct < 16; ++ct) {
        f32x4 acc0 = {0.f, 0.f, 0.f, 0.f};
        f32x4 acc1 = {0.f, 0.f, 0.f, 0.f};
#pragma unroll
        for (int kc = 0; kc < 8; ++kc) {
            bf16x8 bf = *(const bf16x8*)&Wpk[(((ct * 8 + kc) * 64) + lane) * 8];
            acc0 = __builtin_amdgcn_mfma_f32_16x16x32_bf16(afr[0][kc], bf, acc0, 0, 0, 0);
            acc1 = __builtin_amdgcn_mfma_f32_16x16x32_bf16(afr[1][kc], bf, acc1, 0, 0, 0);
        }
        int col = ct * 16 + lrow;
        float b1c = bs1[col];
        float w2c = Ws2[col];
#pragma unroll
        for (int r = 0; r < 4; ++r) {
            p[0][r] += fmaxf(acc0[r] + b1c, 0.f) * w2c;
            p[1][r] += fmaxf(acc1[r] + b1c, 0.f) * w2c;
        }
    }
    // reduce over the 16-lane col dimension
#pragma unroll
    for (int off = 1; off < 16; off <<= 1) {
#pragma unroll
        for (int sp = 0; sp < 2; ++sp)
#pragma unroll
            for (int r = 0; r < 4; ++r)
                p[sp][r] += __shfl_xor(p[sp][r], off, 16);
    }
    const float bs2v = bs2g[0];
    if (lrow == 0) {
#pragma unroll
        for (int sp = 0; sp < 2; ++sp)
#pragma unroll
            for (int r = 0; r < 4; ++r) {
                int rowrel = w * 32 + sp * 16 + quad * 4 + r;
                int n = n0 + rowrel;
                if (n < NSPAN) {
                    float sc = p[sp][r] + bs2v;
                    scores[(size_t)b * NSPAN + n] = (msk[rowrel] > 0.f) ? sc : -INFINITY;
                }
            }
    }
}

// ---------------------------------------------------------------------------
// Kernel 3: per-batch shortlist select. Radix-select 256th largest approx
// score, tau = kth - MARGIN, compact span ids (ascending) with approx >= tau.
// ---------------------------------------------------------------------------
__global__ __launch_bounds__(256) void select_kernel(
    const float* __restrict__ scores,
    int* __restrict__ shortlist, int* __restrict__ slcnt)
{
    const int b = blockIdx.x;
    const int t = threadIdx.x;
    __shared__ unsigned su[NSPAN];
    __shared__ int red[4];
    __shared__ int wave_keep[4];

    const float* sc = scores + (size_t)b * NSPAN;
    for (int i = t; i < NSPAN; i += 256) {
        unsigned ub = __float_as_uint(sc[i]);
        su[i] = (ub & 0x80000000u) ? ~ub : (ub | 0x80000000u);
    }
    __syncthreads();

    unsigned prefix = 0;
    int remaining = KTOP;
    const int wid = t >> 6, lane = t & 63;
    for (int bit = 31; bit >= 0; --bit) {
        unsigned pat = (prefix >> bit) | 1u;
        int cnt = 0;
        for (int i = t; i < NSPAN; i += 256)
            cnt += ((su[i] >> bit) == pat) ? 1 : 0;
#pragma unroll
        for (int off = 32; off > 0; off >>= 1)
            cnt += __shfl_down(cnt, off, 64);
        if (lane == 0) red[wid] = cnt;
        __syncthreads();
        int c = red[0] + red[1] + red[2] + red[3];
        if (c >= remaining) prefix |= (1u << bit);
        else remaining -= c;
        __syncthreads();
    }
    // kth largest approx value -> tau -> key threshold
    unsigned ub = (prefix & 0x80000000u) ? (prefix & 0x7FFFFFFFu) : ~prefix;
    float kthf = __uint_as_float(ub);
    float tau = kthf - MARGIN;
    unsigned tb = __float_as_uint(tau);
    unsigned ktau = (tb & 0x80000000u) ? ~tb : (tb | 0x80000000u);

    int base = 0;
    const unsigned long long ltmask = (1ull << lane) - 1ull;
    for (int c0 = 0; c0 < NSPAN; c0 += 256) {
        int n = c0 + t;
        bool keep = (n < NSPAN) && (su[n] >= ktau);
        unsigned long long bk = __ballot(keep);
        int before = __popcll(bk & ltmask);
        if (lane == 0) wave_keep[wid] = __popcll(bk);
        __syncthreads();
        int kb = base;
        for (int wv = 0; wv < wid; ++wv) kb += wave_keep[wv];
        if (keep) {
            int pos = kb + before;
            if (pos < SCAP) shortlist[b * SCAP + pos] = n;
        }
        for (int wv = 0; wv < 4; ++wv) base += wave_keep[wv];
        __syncthreads();
    }
    if (t == 0) slcnt[b] = base < SCAP ? base : SCAP;
}

// ---------------------------------------------------------------------------
// Kernel 4: exact fp32 scorer on the shortlist (identical arithmetic to the
// R1 score_kernel). Writes exact scores in place over the approx buffer.
// ---------------------------------------------------------------------------
__global__ __launch_bounds__(256) void exact_kernel(
    const float* __restrict__ AE,
    const float* __restrict__ Ws1, const float* __restrict__ bs1,
    const float* __restrict__ Ws2, const float* __restrict__ bs2g,
    const int* __restrict__ s_idx, const int* __restrict__ e_idx,
    const int* __restrict__ shortlist, const int* __restrict__ slcnt,
    float* __restrict__ scores)
{
    const int b  = blockIdx.y;
    const int n0 = blockIdx.x * 128;
    const int cntb = slcnt[b];
    if (n0 >= cntb) return;

    __shared__ float rsh[128][36];
    __shared__ float Ws[32][260];
    __shared__ int   ss[128], se[128], nn[128];

    const int t = threadIdx.x;
    if (t < 128) {
        int row = n0 + t;
        int n = 0;
        if (row < cntb) n = shortlist[b * SCAP + row];
        nn[t] = (row < cntb) ? n : -1;
        ss[t] = s_idx[n]; se[t] = e_idx[n];
    }
    __syncthreads();

    const int tx = t & 31;
    const int ty = t >> 5;
    float acc[16][8];
#pragma unroll
    for (int i = 0; i < 16; ++i)
#pragma unroll
        for (int j = 0; j < 8; ++j) acc[i][j] = 0.f;

    const float* Abase = AE + (size_t)b * T * 512;

    for (int kk = 0; kk < 256; kk += 32) {
        __syncthreads();
        {
            int c4 = (t & 63) * 4, r0 = t >> 6;
#pragma unroll
            for (int r8 = 0; r8 < 8; ++r8) {
                int row = r0 + r8 * 4;
                *(float4*)&Ws[row][c4] =
                    *(const float4*)&Ws1[(size_t)(kk + row) * 256 + c4];
            }
        }
        {
            int sp = t >> 1, k16 = (t & 1) * 16;
            const float* Ar = Abase + (size_t)ss[sp] * 512 + kk + k16;
            const float* Er = Abase + (size_t)se[sp] * 512 + 256 + kk + k16;
#pragma unroll
            for (int q = 0; q < 4; ++q) {
                float4 a = *(const float4*)&Ar[q * 4];
                float4 e = *(const float4*)&Er[q * 4];
                float4 v;
                v.x = fmaxf(a.x + e.x, 0.f); v.y = fmaxf(a.y + e.y, 0.f);
                v.z = fmaxf(a.z + e.z, 0.f); v.w = fmaxf(a.w + e.w, 0.f);
                *(float4*)&rsh[sp][k16 + q * 4] = v;
            }
        }
        __syncthreads();
#pragma unroll
        for (int k4 = 0; k4 < 32; k4 += 4) {
            float w[4][8];
#pragma unroll
            for (int kq = 0; kq < 4; ++kq) {
                float4 w0 = *(const float4*)&Ws[k4 + kq][tx * 8];
                float4 w1 = *(const float4*)&Ws[k4 + kq][tx * 8 + 4];
                w[kq][0] = w0.x; w[kq][1] = w0.y; w[kq][2] = w0.z; w[kq][3] = w0.w;
                w[kq][4] = w1.x; w[kq][5] = w1.y; w[kq][6] = w1.z; w[kq][7] = w1.w;
            }
#pragma unroll
            for (int i = 0; i < 16; ++i) {
                float4 rv = *(const float4*)&rsh[ty * 16 + i][k4];
                float rq[4] = {rv.x, rv.y, rv.z, rv.w};
#pragma unroll
                for (int kq = 0; kq < 4; ++kq)
#pragma unroll
                    for (int j = 0; j < 8; ++j)
                        acc[i][j] = fmaf(rq[kq], w[kq][j], acc[i][j]);
            }
        }
    }

    float b1[8], w2[8];
#pragma unroll
    for (int j = 0; j < 8; ++j) {
        int c = tx * 8 + j;
        b1[j] = bs1[c];
        w2[j] = Ws2[c];
    }
    const float bs2v = bs2g[0];
#pragma unroll
    for (int i = 0; i < 16; ++i) {
        int r = ty * 16 + i;
        float p = 0.f;
#pragma unroll
        for (int j = 0; j < 8; ++j)
            p += fmaxf(acc[i][j] + b1[j], 0.f) * w2[j];
#pragma unroll
        for (int off = 16; off > 0; off >>= 1)
            p += __shfl_down(p, off, 32);
        if (tx == 0) {
            int n = nn[r];
            if (n >= 0)
                scores[(size_t)b * NSPAN + n] = p + bs2v;
        }
    }
}

// ---------------------------------------------------------------------------
// Kernel 5: injection projection
// ---------------------------------------------------------------------------
__global__ __launch_bounds__(256) void inj_kernel(
    const float* __restrict__ tie, const float* __restrict__ Winj,
    const float* __restrict__ binj, float* __restrict__ inj)
{
    int b = blockIdx.x;
    int h = threadIdx.x;
    __shared__ float tb[JJ];
    if (threadIdx.x < JJ) tb[threadIdx.x] = tie[b * JJ + threadIdx.x];
    __syncthreads();
    float a = binj[h];
    for (int j = 0; j < JJ; ++j)
        a = fmaf(tb[j], Winj[j * H + h], a);
    inj[b * H + h] = a;
}

// ---------------------------------------------------------------------------
// Kernel 6: per-batch top-K, jax tie-break, ascending output
// ---------------------------------------------------------------------------
__global__ __launch_bounds__(256) void topk_kernel(
    const float* __restrict__ scores,
    int* __restrict__ top_idx, float* __restrict__ top_scores)
{
    const int b = blockIdx.x;
    const int t = threadIdx.x;
    __shared__ unsigned su[NSPAN];
    __shared__ int red[4];
    __shared__ int wave_eq[4], wave_keep[4];

    const float* sc = scores + (size_t)b * NSPAN;
    for (int i = t; i < NSPAN; i += 256) {
        unsigned ub = __float_as_uint(sc[i]);
        su[i] = (ub & 0x80000000u) ? ~ub : (ub | 0x80000000u);
    }
    __syncthreads();

    unsigned prefix = 0;
    int remaining = KTOP;
    const int wid = t >> 6, lane = t & 63;
    for (int bit = 31; bit >= 0; --bit) {
        unsigned pat = (prefix >> bit) | 1u;
        int cnt = 0;
        for (int i = t; i < NSPAN; i += 256)
            cnt += ((su[i] >> bit) == pat) ? 1 : 0;
#pragma unroll
        for (int off = 32; off > 0; off >>= 1)
            cnt += __shfl_down(cnt, off, 64);
        if (lane == 0) red[wid] = cnt;
        __syncthreads();
        int c = red[0] + red[1] + red[2] + red[3];
        if (c >= remaining) prefix |= (1u << bit);
        else remaining -= c;
        __syncthreads();
    }
    const unsigned v = prefix;
    const int need_eq = remaining;

    int base_eq = 0, base_keep = 0;
    const unsigned long long ltmask = (1ull << lane) - 1ull;
    for (int c0 = 0; c0 < NSPAN; c0 += 256) {
        int n = c0 + t;
        bool valid = n < NSPAN;
        unsigned u = valid ? su[n] : 0u;
        bool eq = valid && (u == v);
        bool gt = valid && (u > v);
        unsigned long long beq = __ballot(eq);
        int eq_before = __popcll(beq & ltmask);
        if (lane == 0) wave_eq[wid] = __popcll(beq);
        __syncthreads();
        int eqb = base_eq;
        for (int w = 0; w < wid; ++w) eqb += wave_eq[w];
        int eq_rank = eqb + eq_before;
        bool keep = gt || (eq && (eq_rank < need_eq));
        unsigned long long bk = __ballot(keep);
        int keep_before = __popcll(bk & ltmask);
        if (lane == 0) wave_keep[wid] = __popcll(bk);
        __syncthreads();
        int kb = base_keep;
        for (int w = 0; w < wid; ++w) kb += wave_keep[w];
        if (keep) {
            int pos = kb + keep_before;
            top_idx[b * KTOP + pos] = n;
            unsigned fb = (u & 0x80000000u) ? (u & 0x7FFFFFFFu) : ~u;
            float f = __uint_as_float(fb);
            top_scores[b * KTOP + pos] = isinf(f) ? -1.0f : f;
        }
        for (int w = 0; w < 4; ++w) { base_eq += wave_eq[w]; base_keep += wave_keep[w]; }
        __syncthreads();
    }
}

// ---------------------------------------------------------------------------
// Kernel 7: final head
// ---------------------------------------------------------------------------
__global__ __launch_bounds__(256) void final_kernel(
    const float* __restrict__ AE,
    const int* __restrict__ s_idx, const int* __restrict__ e_idx,
    const int* __restrict__ maskp,
    const int* __restrict__ top_idx, const float* __restrict__ top_scores,
    const float* __restrict__ injv,
    const float* __restrict__ Wsec, const float* __restrict__ bsec,
    const float* __restrict__ Wpred, const float* __restrict__ bpredg,
    float* __restrict__ out)
{
    const int b = blockIdx.x >> 2;
    const int k0 = (blockIdx.x & 3) * 64;

    __shared__ float sh[64][36];
    __shared__ float Ws[32][260];
    __shared__ int ss[64], se[64];
    __shared__ float msk[64], tsc[64];

    const int t = threadIdx.x;
    if (t < 64) {
        int kidx = k0 + t;
        int n = top_idx[b * KTOP + kidx];
        int s = s_idx[n], e = e_idx[n];
        ss[t] = s; se[t] = e;
        msk[t] = (maskp[b * T + s] != 0 && maskp[b * T + e] != 0) ? 1.f : 0.f;
        tsc[t] = top_scores[b * KTOP + kidx];
    }
    __syncthreads();

    const int tx = t & 31;
    const int ty = t >> 5;
    float acc[8][8];
#pragma unroll
    for (int i = 0; i < 8; ++i)
#pragma unroll
        for (int j = 0; j < 8; ++j) acc[i][j] = 0.f;

    const float* Abase = AE + (size_t)b * T * 512;

    for (int kk = 0; kk < 256; kk += 32) {
        __syncthreads();
        {
            int c4 = (t & 63) * 4, r0 = t >> 6;
#pragma unroll
            for (int r8 = 0; r8 < 8; ++r8) {
                int row = r0 + r8 * 4;
                *(float4*)&Ws[row][c4] =
                    *(const float4*)&Wsec[(size_t)(kk + row) * 256 + c4];
            }
        }
        {
            int sp = t >> 2, k8 = (t & 3) * 8;
            const float* Ar = Abase + (size_t)ss[sp] * 512 + kk + k8;
            const float* Er = Abase + (size_t)se[sp] * 512 + 256 + kk + k8;
#pragma unroll
            for (int q = 0; q < 2; ++q) {
                float4 a = *(const float4*)&Ar[q * 4];
                float4 e = *(const float4*)&Er[q * 4];
                float4 v;
                v.x = a.x + e.x; v.y = a.y + e.y; v.z = a.z + e.z; v.w = a.w + e.w;
                *(float4*)&sh[sp][k8 + q * 4] = v;
            }
        }
        __syncthreads();
#pragma unroll
        for (int k4 = 0; k4 < 32; k4 += 4) {
            float w[4][8];
#pragma unroll
            for (int kq = 0; kq < 4; ++kq) {
                float4 w0 = *(const float4*)&Ws[k4 + kq][tx * 8];
                float4 w1 = *(const float4*)&Ws[k4 + kq][tx * 8 + 4];
                w[kq][0] = w0.x; w[kq][1] = w0.y; w[kq][2] = w0.z; w[kq][3] = w0.w;
                w[kq][4] = w1.x; w[kq][5] = w1.y; w[kq][6] = w1.z; w[kq][7] = w1.w;
            }
#pragma unroll
            for (int i = 0; i < 8; ++i) {
                float4 rv = *(const float4*)&sh[ty * 8 + i][k4];
                float rq[4] = {rv.x, rv.y, rv.z, rv.w};
#pragma unroll
                for (int kq = 0; kq < 4; ++kq)
#pragma unroll
                    for (int j = 0; j < 8; ++j)
                        acc[i][j] = fmaf(rq[kq], w[kq][j], acc[i][j]);
            }
        }
    }

    float bsec_r[8], wpred_r[8], injr[8];
#pragma unroll
    for (int j = 0; j < 8; ++j) {
        int c = tx * 8 + j;
        bsec_r[j] = bsec[c];
        wpred_r[j] = Wpred[c];
        injr[j] = injv[b * H + c];
    }
    const float bp = bpredg[0];
#pragma unroll
    for (int i = 0; i < 8; ++i) {
        int r = ty * 8 + i;
        float p = 0.f;
#pragma unroll
        for (int j = 0; j < 8; ++j) {
            float sec = acc[i][j] + bsec_r[j];
            p += fmaxf(injr[j] + sec, 0.f) * wpred_r[j];
        }
#pragma unroll
        for (int off = 16; off > 0; off >>= 1)
            p += __shfl_down(p, off, 32);
        if (tx == 0) {
            float logit = p + bp + tsc[r];
            float prob = (1.f / (1.f + expf(-logit))) * msk[r];
            out[b * KTOP + k0 + r] = prob;
        }
    }
}

// ---------------------------------------------------------------------------
extern "C" void kernel_launch(void* const* d_in, const int* in_sizes, int n_in,
                              void* d_out, int out_size, void* d_ws, size_t ws_size,
                              hipStream_t stream) {
    const float* inputs  = (const float*)d_in[0];
    const int*   imask   = (const int*)d_in[1];
    const float* tie     = (const float*)d_in[2];
    const float* W_start = (const float*)d_in[3];
    const float* b_start = (const float*)d_in[4];
    const float* W_end   = (const float*)d_in[5];
    const float* b_end   = (const float*)d_in[6];
    const float* W_s1    = (const float*)d_in[7];
    const float* b_s1    = (const float*)d_in[8];
    const float* W_s2    = (const float*)d_in[9];
    const float* b_s2    = (const float*)d_in[10];
    const float* W_inj   = (const float*)d_in[11];
    const float* b_inj   = (const float*)d_in[12];
    const float* W_sec   = (const float*)d_in[13];
    const float* b_sec   = (const float*)d_in[14];
    const float* W_pred  = (const float*)d_in[15];
    const float* b_pred  = (const float*)d_in[16];
    float* out = (float*)d_out;

    // ws layout (floats): AE | scores | s_idx | e_idx | top_idx | top_scores |
    //                     inj | Wpk(bf16, 65536 ushort = 32768 fl) | shortlist | slcnt
    float* AE         = (float*)d_ws;
    float* scores     = AE + (size_t)BB * T * 512;            // 4,194,304
    int*   s_idx      = (int*)(scores + (size_t)BB * NSPAN);  // +528,384
    int*   e_idx      = s_idx + NSPAN;
    int*   top_idx    = e_idx + NSPAN;
    float* top_scores = (float*)(top_idx + BB * KTOP);
    float* injv       = top_scores + BB * KTOP;
    unsigned short* Wpk = (unsigned short*)(injv + BB * H);
    int*   shortlist  = (int*)(Wpk + 65536);
    int*   slcnt      = shortlist + BB * SCAP;

    build_idx_kernel<<<1, 128, 0, stream>>>(s_idx, e_idx);
    proj_kernel<<<dim3(128, 4), 256, 0, stream>>>(inputs, W_start, b_start, W_end, b_end, AE);
    wpack_kernel<<<256, 256, 0, stream>>>(W_s1, Wpk);
    approx_kernel<<<dim3(65, BB), 256, 0, stream>>>(AE, Wpk, b_s1, W_s2, b_s2,
                                                    s_idx, e_idx, imask, scores);
    select_kernel<<<BB, 256, 0, stream>>>(scores, shortlist, slcnt);
    exact_kernel<<<dim3(8, BB), 256, 0, stream>>>(AE, W_s1, b_s1, W_s2, b_s2,
                                                  s_idx, e_idx, shortlist, slcnt, scores);
    inj_kernel<<<BB, 256, 0, stream>>>(tie, W_inj, b_inj, injv);
    topk_kernel<<<BB, 256, 0, stream>>>(scores, top_idx, top_scores);
    final_kernel<<<BB * 4, 256, 0, stream>>>(AE, s_idx, e_idx, imask, top_idx, top_scores,
                                             injv, W_sec, b_sec, W_pred, b_pred, out);
}

// Round 3
// 623.717 us; speedup vs baseline: 2.5423x; 1.0322x over previous
//
#include <hip/hip_runtime.h>
#include <math.h>

#define BB 64
#define T 128
#define DD 768
#define H 256
#define JJ 128
#define NSPAN 8256
#define KTOP 256
#define SCAP 1024
#define MARGIN 0.03f

typedef __attribute__((ext_vector_type(8))) short bf16x8;
typedef __attribute__((ext_vector_type(4))) float f32x4;
typedef __attribute__((ext_vector_type(8))) unsigned short us8;

__device__ inline unsigned short bfrne(float x) {
    unsigned u = __float_as_uint(x);
    return (unsigned short)((u + 0x7FFFu + ((u >> 16) & 1u)) >> 16);
}

// ---------------------------------------------------------------------------
// Kernel 0: triu span index tables (start-major, matches jnp.triu_indices)
// ---------------------------------------------------------------------------
__global__ void build_idx_kernel(int* s_idx, int* e_idx) {
    int s = threadIdx.x;
    if (s < T) {
        int start = s * T - (s * (s - 1)) / 2;
        int len = T - s;
        for (int i = 0; i < len; ++i) {
            s_idx[start + i] = s;
            e_idx[start + i] = s + i;
        }
    }
}

// ---------------------------------------------------------------------------
// Kernel 1: proj GEMM (unchanged this round)
// ---------------------------------------------------------------------------
__global__ __launch_bounds__(256) void proj_kernel(
    const float* __restrict__ X,
    const float* __restrict__ Wa, const float* __restrict__ ba,
    const float* __restrict__ Wb, const float* __restrict__ bb,
    float* __restrict__ AE)
{
    const int m0 = blockIdx.x * 64;
    const int c0 = blockIdx.y * 128;
    const float* W;
    const float* bias;
    int wc0;
    if (c0 < 256) { W = Wa; bias = ba; wc0 = c0; }
    else          { W = Wb; bias = bb; wc0 = c0 - 256; }

    __shared__ float Xs[64][20];
    __shared__ float Ws[16][132];

    const int t  = threadIdx.x;
    const int tx = t & 31;
    const int ty = t >> 5;

    float acc[8][4];
#pragma unroll
    for (int i = 0; i < 8; ++i)
#pragma unroll
        for (int j = 0; j < 4; ++j) acc[i][j] = 0.f;

    for (int kk = 0; kk < DD; kk += 16) {
        __syncthreads();
        {
            int row = t >> 2, k4 = (t & 3) * 4;
            float4 v = *(const float4*)&X[(size_t)(m0 + row) * DD + kk + k4];
            *(float4*)&Xs[row][k4] = v;
        }
        {
            int row = t >> 4, c8 = (t & 15) * 8;
            float4 w0 = *(const float4*)&W[(size_t)(kk + row) * 256 + wc0 + c8];
            float4 w1 = *(const float4*)&W[(size_t)(kk + row) * 256 + wc0 + c8 + 4];
            *(float4*)&Ws[row][c8]     = w0;
            *(float4*)&Ws[row][c8 + 4] = w1;
        }
        __syncthreads();
#pragma unroll
        for (int k4 = 0; k4 < 16; k4 += 4) {
            float w[4][4];
#pragma unroll
            for (int kq = 0; kq < 4; ++kq) {
                float4 wv = *(const float4*)&Ws[k4 + kq][tx * 4];
                w[kq][0] = wv.x; w[kq][1] = wv.y; w[kq][2] = wv.z; w[kq][3] = wv.w;
            }
#pragma unroll
            for (int i = 0; i < 8; ++i) {
                float4 xv = *(const float4*)&Xs[ty * 8 + i][k4];
                float xq[4] = {xv.x, xv.y, xv.z, xv.w};
#pragma unroll
                for (int kq = 0; kq < 4; ++kq)
#pragma unroll
                    for (int j = 0; j < 4; ++j)
                        acc[i][j] = fmaf(xq[kq], w[kq][j], acc[i][j]);
            }
        }
    }
    float bj[4];
#pragma unroll
    for (int j = 0; j < 4; ++j) bj[j] = bias[wc0 + tx * 4 + j];
#pragma unroll
    for (int i = 0; i < 8; ++i) {
        float4 o;
        o.x = acc[i][0] + bj[0]; o.y = acc[i][1] + bj[1];
        o.z = acc[i][2] + bj[2]; o.w = acc[i][3] + bj[3];
        *(float4*)&AE[(size_t)(m0 + ty * 8 + i) * 512 + c0 + tx * 4] = o;
    }
}

// ---------------------------------------------------------------------------
// Kernel 1b: pack W_s1 into bf16 MFMA B-fragment layout.
// ---------------------------------------------------------------------------
__global__ __launch_bounds__(256) void wpack_kernel(
    const float* __restrict__ W1, unsigned short* __restrict__ Wpk)
{
    int idx = blockIdx.x * 256 + threadIdx.x;   // 65536 total
    int j  = idx & 7;
    int l  = (idx >> 3) & 63;
    int kc = (idx >> 9) & 7;
    int ct = idx >> 12;
    int k = kc * 32 + (l >> 4) * 8 + j;
    int n = ct * 16 + (l & 15);
    Wpk[idx] = bfrne(W1[k * 256 + n]);
}

// ---------------------------------------------------------------------------
// Kernel 2: approximate span scorer via bf16 MFMA 16x16x32.
// ct-split across waves: wave w owns N-cols [w*64, w*64+64) (4 ct tiles, held
// as register B fragments, each Wpk fragment read ONCE per block from L2).
// A fragments from LDS; layer-2 partials cross-wave reduced via LDS.
// ---------------------------------------------------------------------------
__global__ __launch_bounds__(256) void approx_kernel(
    const float* __restrict__ AE,
    const unsigned short* __restrict__ Wpk,
    const float* __restrict__ bs1, const float* __restrict__ Ws2,
    const float* __restrict__ bs2g,
    const int* __restrict__ s_idx, const int* __restrict__ e_idx,
    const int* __restrict__ maskp,
    float* __restrict__ scores)
{
    const int b  = blockIdx.y;
    const int n0 = blockIdx.x * 128;

    __shared__ unsigned short rsh[128][264];   // bf16, padded
    __shared__ float pslice[4][128];
    __shared__ int   ss[128], se[128];
    __shared__ float msk[128];

    const int t = threadIdx.x;
    if (t < 128) {
        int n = n0 + t;
        int s = 0, e = 0;
        float mv = 0.f;
        if (n < NSPAN) {
            s = s_idx[n]; e = e_idx[n];
            mv = (maskp[b * T + s] != 0 && maskp[b * T + e] != 0) ? 1.f : 0.f;
        }
        ss[t] = s; se[t] = e; msk[t] = mv;
    }
    __syncthreads();

    const float* Abase = AE + (size_t)b * T * 512;
    {   // stage relu(A[s]+E[e]) as bf16
        int sp = t >> 1;
        int kbase = (t & 1) * 128;
        const float* Ar = Abase + (size_t)ss[sp] * 512 + kbase;
        const float* Er = Abase + (size_t)se[sp] * 512 + 256 + kbase;
        unsigned short* dst = &rsh[sp][kbase];
#pragma unroll
        for (int i = 0; i < 16; ++i) {
            float4 a0 = *(const float4*)&Ar[i * 8];
            float4 a1 = *(const float4*)&Ar[i * 8 + 4];
            float4 e0 = *(const float4*)&Er[i * 8];
            float4 e1 = *(const float4*)&Er[i * 8 + 4];
            us8 v;
            v[0] = bfrne(fmaxf(a0.x + e0.x, 0.f));
            v[1] = bfrne(fmaxf(a0.y + e0.y, 0.f));
            v[2] = bfrne(fmaxf(a0.z + e0.z, 0.f));
            v[3] = bfrne(fmaxf(a0.w + e0.w, 0.f));
            v[4] = bfrne(fmaxf(a1.x + e1.x, 0.f));
            v[5] = bfrne(fmaxf(a1.y + e1.y, 0.f));
            v[6] = bfrne(fmaxf(a1.z + e1.z, 0.f));
            v[7] = bfrne(fmaxf(a1.w + e1.w, 0.f));
            *(us8*)&dst[i * 8] = v;
        }
    }
    __syncthreads();

    const int w    = t >> 6;      // wave 0..3 -> ct tiles [w*4, w*4+4)
    const int lane = t & 63;
    const int lrow = lane & 15;
    const int quad = lane >> 4;

    float pp[8][4];
#pragma unroll
    for (int sp = 0; sp < 8; ++sp)
#pragma unroll
        for (int r = 0; r < 4; ++r) pp[sp][r] = 0.f;

#pragma unroll
    for (int ctp = 0; ctp < 2; ++ctp) {
        const int ctbase = w * 4 + ctp * 2;
        bf16x8 bfr[2][8];
        float b1c[2], w2c[2];
#pragma unroll
        for (int c2 = 0; c2 < 2; ++c2) {
#pragma unroll
            for (int kc = 0; kc < 8; ++kc)
                bfr[c2][kc] = *(const bf16x8*)&Wpk[((((ctbase + c2) * 8 + kc) * 64) + lane) * 8];
            int col = (ctbase + c2) * 16 + lrow;
            b1c[c2] = bs1[col];
            w2c[c2] = Ws2[col];
        }
#pragma unroll
        for (int sp = 0; sp < 8; ++sp) {
            bf16x8 afr[8];
#pragma unroll
            for (int kc = 0; kc < 8; ++kc)
                afr[kc] = *(const bf16x8*)&rsh[sp * 16 + lrow][kc * 32 + quad * 8];
#pragma unroll
            for (int c2 = 0; c2 < 2; ++c2) {
                f32x4 acc = {0.f, 0.f, 0.f, 0.f};
#pragma unroll
                for (int kc = 0; kc < 8; ++kc)
                    acc = __builtin_amdgcn_mfma_f32_16x16x32_bf16(afr[kc], bfr[c2][kc], acc, 0, 0, 0);
#pragma unroll
                for (int r = 0; r < 4; ++r)
                    pp[sp][r] += fmaxf(acc[r] + b1c[c2], 0.f) * w2c[c2];
            }
        }
    }
    // reduce over the 16-lane col dimension
#pragma unroll
    for (int off = 1; off < 16; off <<= 1)
#pragma unroll
        for (int sp = 0; sp < 8; ++sp)
#pragma unroll
            for (int r = 0; r < 4; ++r)
                pp[sp][r] += __shfl_xor(pp[sp][r], off, 16);
    if (lrow == 0) {
#pragma unroll
        for (int sp = 0; sp < 8; ++sp)
#pragma unroll
            for (int r = 0; r < 4; ++r)
                pslice[w][sp * 16 + quad * 4 + r] = pp[sp][r];
    }
    __syncthreads();
    if (t < 128) {
        int n = n0 + t;
        if (n < NSPAN) {
            float sc = pslice[0][t] + pslice[1][t] + pslice[2][t] + pslice[3][t] + bs2g[0];
            scores[(size_t)b * NSPAN + n] = (msk[t] > 0.f) ? sc : -INFINITY;
        }
    }
}

// ---------------------------------------------------------------------------
// Kernel 3: per-batch shortlist select (radix-select kth, keep >= kth-MARGIN)
// ---------------------------------------------------------------------------
__global__ __launch_bounds__(256) void select_kernel(
    const float* __restrict__ scores,
    int* __restrict__ shortlist, int* __restrict__ slcnt)
{
    const int b = blockIdx.x;
    const int t = threadIdx.x;
    __shared__ unsigned su[NSPAN];
    __shared__ int red[4];
    __shared__ int wave_keep[4];

    const float* sc = scores + (size_t)b * NSPAN;
    for (int i = t; i < NSPAN; i += 256) {
        unsigned ub = __float_as_uint(sc[i]);
        su[i] = (ub & 0x80000000u) ? ~ub : (ub | 0x80000000u);
    }
    __syncthreads();

    unsigned prefix = 0;
    int remaining = KTOP;
    const int wid = t >> 6, lane = t & 63;
    for (int bit = 31; bit >= 0; --bit) {
        unsigned pat = (prefix >> bit) | 1u;
        int cnt = 0;
        for (int i = t; i < NSPAN; i += 256)
            cnt += ((su[i] >> bit) == pat) ? 1 : 0;
#pragma unroll
        for (int off = 32; off > 0; off >>= 1)
            cnt += __shfl_down(cnt, off, 64);
        if (lane == 0) red[wid] = cnt;
        __syncthreads();
        int c = red[0] + red[1] + red[2] + red[3];
        if (c >= remaining) prefix |= (1u << bit);
        else remaining -= c;
        __syncthreads();
    }
    unsigned ub = (prefix & 0x80000000u) ? (prefix & 0x7FFFFFFFu) : ~prefix;
    float kthf = __uint_as_float(ub);
    float tau = kthf - MARGIN;
    unsigned tb = __float_as_uint(tau);
    unsigned ktau = (tb & 0x80000000u) ? ~tb : (tb | 0x80000000u);

    int base = 0;
    const unsigned long long ltmask = (1ull << lane) - 1ull;
    for (int c0 = 0; c0 < NSPAN; c0 += 256) {
        int n = c0 + t;
        bool keep = (n < NSPAN) && (su[n] >= ktau);
        unsigned long long bk = __ballot(keep);
        int before = __popcll(bk & ltmask);
        if (lane == 0) wave_keep[wid] = __popcll(bk);
        __syncthreads();
        int kb = base;
        for (int wv = 0; wv < wid; ++wv) kb += wave_keep[wv];
        if (keep) {
            int pos = kb + before;
            if (pos < SCAP) shortlist[b * SCAP + pos] = n;
        }
        for (int wv = 0; wv < 4; ++wv) base += wave_keep[wv];
        __syncthreads();
    }
    if (t == 0) slcnt[b] = base < SCAP ? base : SCAP;
}

// ---------------------------------------------------------------------------
// Kernel 4: exact fp32 scorer on the shortlist. 64-span blocks (16/batch) for
// occupancy; conflict-free LDS col mapping {4tx, 128+4tx}.
// ---------------------------------------------------------------------------
__global__ __launch_bounds__(256) void exact_kernel(
    const float* __restrict__ AE,
    const float* __restrict__ Ws1, const float* __restrict__ bs1,
    const float* __restrict__ Ws2, const float* __restrict__ bs2g,
    const int* __restrict__ s_idx, const int* __restrict__ e_idx,
    const int* __restrict__ shortlist, const int* __restrict__ slcnt,
    float* __restrict__ scores)
{
    const int b  = blockIdx.y;
    const int n0 = blockIdx.x * 64;
    const int cntb = slcnt[b];
    if (n0 >= cntb) return;

    __shared__ float rsh[64][36];
    __shared__ float Ws[32][260];
    __shared__ int   ss[64], se[64], nn[64];

    const int t = threadIdx.x;
    if (t < 64) {
        int row = n0 + t;
        int n = 0;
        if (row < cntb) n = shortlist[b * SCAP + row];
        nn[t] = (row < cntb) ? n : -1;
        ss[t] = s_idx[n]; se[t] = e_idx[n];
    }
    __syncthreads();

    const int tx = t & 31;
    const int ty = t >> 5;
    float acc[8][8];
#pragma unroll
    for (int i = 0; i < 8; ++i)
#pragma unroll
        for (int j = 0; j < 8; ++j) acc[i][j] = 0.f;

    const float* Abase = AE + (size_t)b * T * 512;

    for (int kk = 0; kk < 256; kk += 32) {
        __syncthreads();
        {
            int c4 = (t & 63) * 4, r0 = t >> 6;
#pragma unroll
            for (int r8 = 0; r8 < 8; ++r8) {
                int row = r0 + r8 * 4;
                *(float4*)&Ws[row][c4] =
                    *(const float4*)&Ws1[(size_t)(kk + row) * 256 + c4];
            }
        }
        {
            int sp = t >> 2, k8 = (t & 3) * 8;
            const float* Ar = Abase + (size_t)ss[sp] * 512 + kk + k8;
            const float* Er = Abase + (size_t)se[sp] * 512 + 256 + kk + k8;
#pragma unroll
            for (int q = 0; q < 2; ++q) {
                float4 a = *(const float4*)&Ar[q * 4];
                float4 e = *(const float4*)&Er[q * 4];
                float4 v;
                v.x = fmaxf(a.x + e.x, 0.f); v.y = fmaxf(a.y + e.y, 0.f);
                v.z = fmaxf(a.z + e.z, 0.f); v.w = fmaxf(a.w + e.w, 0.f);
                *(float4*)&rsh[sp][k8 + q * 4] = v;
            }
        }
        __syncthreads();
#pragma unroll
        for (int k4 = 0; k4 < 32; k4 += 4) {
            float w[4][8];
#pragma unroll
            for (int kq = 0; kq < 4; ++kq) {
                float4 w0 = *(const float4*)&Ws[k4 + kq][tx * 4];
                float4 w1 = *(const float4*)&Ws[k4 + kq][128 + tx * 4];
                w[kq][0] = w0.x; w[kq][1] = w0.y; w[kq][2] = w0.z; w[kq][3] = w0.w;
                w[kq][4] = w1.x; w[kq][5] = w1.y; w[kq][6] = w1.z; w[kq][7] = w1.w;
            }
#pragma unroll
            for (int i = 0; i < 8; ++i) {
                float4 rv = *(const float4*)&rsh[ty * 8 + i][k4];
                float rq[4] = {rv.x, rv.y, rv.z, rv.w};
#pragma unroll
                for (int kq = 0; kq < 4; ++kq)
#pragma unroll
                    for (int j = 0; j < 8; ++j)
                        acc[i][j] = fmaf(rq[kq], w[kq][j], acc[i][j]);
            }
        }
    }

    float b1[8], w2[8];
#pragma unroll
    for (int j = 0; j < 8; ++j) {
        int c = (j < 4) ? (tx * 4 + j) : (128 + tx * 4 + j - 4);
        b1[j] = bs1[c];
        w2[j] = Ws2[c];
    }
    const float bs2v = bs2g[0];
#pragma unroll
    for (int i = 0; i < 8; ++i) {
        int r = ty * 8 + i;
        float p = 0.f;
#pragma unroll
        for (int j = 0; j < 8; ++j)
            p += fmaxf(acc[i][j] + b1[j], 0.f) * w2[j];
#pragma unroll
        for (int off = 16; off > 0; off >>= 1)
            p += __shfl_down(p, off, 32);
        if (tx == 0) {
            int n = nn[r];
            if (n >= 0)
                scores[(size_t)b * NSPAN + n] = p + bs2v;
        }
    }
}

// ---------------------------------------------------------------------------
// Kernel 5: injection projection
// ---------------------------------------------------------------------------
__global__ __launch_bounds__(256) void inj_kernel(
    const float* __restrict__ tie, const float* __restrict__ Winj,
    const float* __restrict__ binj, float* __restrict__ inj)
{
    int b = blockIdx.x;
    int h = threadIdx.x;
    __shared__ float tb[JJ];
    if (threadIdx.x < JJ) tb[threadIdx.x] = tie[b * JJ + threadIdx.x];
    __syncthreads();
    float a = binj[h];
    for (int j = 0; j < JJ; ++j)
        a = fmaf(tb[j], Winj[j * H + h], a);
    inj[b * H + h] = a;
}

// ---------------------------------------------------------------------------
// Kernel 6: per-batch top-K, jax tie-break, ascending output
// ---------------------------------------------------------------------------
__global__ __launch_bounds__(256) void topk_kernel(
    const float* __restrict__ scores,
    int* __restrict__ top_idx, float* __restrict__ top_scores)
{
    const int b = blockIdx.x;
    const int t = threadIdx.x;
    __shared__ unsigned su[NSPAN];
    __shared__ int red[4];
    __shared__ int wave_eq[4], wave_keep[4];

    const float* sc = scores + (size_t)b * NSPAN;
    for (int i = t; i < NSPAN; i += 256) {
        unsigned ub = __float_as_uint(sc[i]);
        su[i] = (ub & 0x80000000u) ? ~ub : (ub | 0x80000000u);
    }
    __syncthreads();

    unsigned prefix = 0;
    int remaining = KTOP;
    const int wid = t >> 6, lane = t & 63;
    for (int bit = 31; bit >= 0; --bit) {
        unsigned pat = (prefix >> bit) | 1u;
        int cnt = 0;
        for (int i = t; i < NSPAN; i += 256)
            cnt += ((su[i] >> bit) == pat) ? 1 : 0;
#pragma unroll
        for (int off = 32; off > 0; off >>= 1)
            cnt += __shfl_down(cnt, off, 64);
        if (lane == 0) red[wid] = cnt;
        __syncthreads();
        int c = red[0] + red[1] + red[2] + red[3];
        if (c >= remaining) prefix |= (1u << bit);
        else remaining -= c;
        __syncthreads();
    }
    const unsigned v = prefix;
    const int need_eq = remaining;

    int base_eq = 0, base_keep = 0;
    const unsigned long long ltmask = (1ull << lane) - 1ull;
    for (int c0 = 0; c0 < NSPAN; c0 += 256) {
        int n = c0 + t;
        bool valid = n < NSPAN;
        unsigned u = valid ? su[n] : 0u;
        bool eq = valid && (u == v);
        bool gt = valid && (u > v);
        unsigned long long beq = __ballot(eq);
        int eq_before = __popcll(beq & ltmask);
        if (lane == 0) wave_eq[wid] = __popcll(beq);
        __syncthreads();
        int eqb = base_eq;
        for (int w = 0; w < wid; ++w) eqb += wave_eq[w];
        int eq_rank = eqb + eq_before;
        bool keep = gt || (eq && (eq_rank < need_eq));
        unsigned long long bk = __ballot(keep);
        int keep_before = __popcll(bk & ltmask);
        if (lane == 0) wave_keep[wid] = __popcll(bk);
        __syncthreads();
        int kb = base_keep;
        for (int w = 0; w < wid; ++w) kb += wave_keep[w];
        if (keep) {
            int pos = kb + keep_before;
            top_idx[b * KTOP + pos] = n;
            unsigned fb = (u & 0x80000000u) ? (u & 0x7FFFFFFFu) : ~u;
            float f = __uint_as_float(fb);
            top_scores[b * KTOP + pos] = isinf(f) ? -1.0f : f;
        }
        for (int w = 0; w < 4; ++w) { base_eq += wave_eq[w]; base_keep += wave_keep[w]; }
        __syncthreads();
    }
}

// ---------------------------------------------------------------------------
// Kernel 7: final head (conflict-free col mapping)
// ---------------------------------------------------------------------------
__global__ __launch_bounds__(256) void final_kernel(
    const float* __restrict__ AE,
    const int* __restrict__ s_idx, const int* __restrict__ e_idx,
    const int* __restrict__ maskp,
    const int* __restrict__ top_idx, const float* __restrict__ top_scores,
    const float* __restrict__ injv,
    const float* __restrict__ Wsec, const float* __restrict__ bsec,
    const float* __restrict__ Wpred, const float* __restrict__ bpredg,
    float* __restrict__ out)
{
    const int b = blockIdx.x >> 2;
    const int k0 = (blockIdx.x & 3) * 64;

    __shared__ float sh[64][36];
    __shared__ float Ws[32][260];
    __shared__ int ss[64], se[64];
    __shared__ float msk[64], tsc[64];

    const int t = threadIdx.x;
    if (t < 64) {
        int kidx = k0 + t;
        int n = top_idx[b * KTOP + kidx];
        int s = s_idx[n], e = e_idx[n];
        ss[t] = s; se[t] = e;
        msk[t] = (maskp[b * T + s] != 0 && maskp[b * T + e] != 0) ? 1.f : 0.f;
        tsc[t] = top_scores[b * KTOP + kidx];
    }
    __syncthreads();

    const int tx = t & 31;
    const int ty = t >> 5;
    float acc[8][8];
#pragma unroll
    for (int i = 0; i < 8; ++i)
#pragma unroll
        for (int j = 0; j < 8; ++j) acc[i][j] = 0.f;

    const float* Abase = AE + (size_t)b * T * 512;

    for (int kk = 0; kk < 256; kk += 32) {
        __syncthreads();
        {
            int c4 = (t & 63) * 4, r0 = t >> 6;
#pragma unroll
            for (int r8 = 0; r8 < 8; ++r8) {
                int row = r0 + r8 * 4;
                *(float4*)&Ws[row][c4] =
                    *(const float4*)&Wsec[(size_t)(kk + row) * 256 + c4];
            }
        }
        {
            int sp = t >> 2, k8 = (t & 3) * 8;
            const float* Ar = Abase + (size_t)ss[sp] * 512 + kk + k8;
            const float* Er = Abase + (size_t)se[sp] * 512 + 256 + kk + k8;
#pragma unroll
            for (int q = 0; q < 2; ++q) {
                float4 a = *(const float4*)&Ar[q * 4];
                float4 e = *(const float4*)&Er[q * 4];
                float4 v;
                v.x = a.x + e.x; v.y = a.y + e.y; v.z = a.z + e.z; v.w = a.w + e.w;
                *(float4*)&sh[sp][k8 + q * 4] = v;
            }
        }
        __syncthreads();
#pragma unroll
        for (int k4 = 0; k4 < 32; k4 += 4) {
            float w[4][8];
#pragma unroll
            for (int kq = 0; kq < 4; ++kq) {
                float4 w0 = *(const float4*)&Ws[k4 + kq][tx * 4];
                float4 w1 = *(const float4*)&Ws[k4 + kq][128 + tx * 4];
                w[kq][0] = w0.x; w[kq][1] = w0.y; w[kq][2] = w0.z; w[kq][3] = w0.w;
                w[kq][4] = w1.x; w[kq][5] = w1.y; w[kq][6] = w1.z; w[kq][7] = w1.w;
            }
#pragma unroll
            for (int i = 0; i < 8; ++i) {
                float4 rv = *(const float4*)&sh[ty * 8 + i][k4];
                float rq[4] = {rv.x, rv.y, rv.z, rv.w};
#pragma unroll
                for (int kq = 0; kq < 4; ++kq)
#pragma unroll
                    for (int j = 0; j < 8; ++j)
                        acc[i][j] = fmaf(rq[kq], w[kq][j], acc[i][j]);
            }
        }
    }

    float bsec_r[8], wpred_r[8], injr[8];
#pragma unroll
    for (int j = 0; j < 8; ++j) {
        int c = (j < 4) ? (tx * 4 + j) : (128 + tx * 4 + j - 4);
        bsec_r[j] = bsec[c];
        wpred_r[j] = Wpred[c];
        injr[j] = injv[b * H + c];
    }
    const float bp = bpredg[0];
#pragma unroll
    for (int i = 0; i < 8; ++i) {
        int r = ty * 8 + i;
        float p = 0.f;
#pragma unroll
        for (int j = 0; j < 8; ++j) {
            float sec = acc[i][j] + bsec_r[j];
            p += fmaxf(injr[j] + sec, 0.f) * wpred_r[j];
        }
#pragma unroll
        for (int off = 16; off > 0; off >>= 1)
            p += __shfl_down(p, off, 32);
        if (tx == 0) {
            float logit = p + bp + tsc[r];
            float prob = (1.f / (1.f + expf(-logit))) * msk[r];
            out[b * KTOP + k0 + r] = prob;
        }
    }
}

// ---------------------------------------------------------------------------
extern "C" void kernel_launch(void* const* d_in, const int* in_sizes, int n_in,
                              void* d_out, int out_size, void* d_ws, size_t ws_size,
                              hipStream_t stream) {
    const float* inputs  = (const float*)d_in[0];
    const int*   imask   = (const int*)d_in[1];
    const float* tie     = (const float*)d_in[2];
    const float* W_start = (const float*)d_in[3];
    const float* b_start = (const float*)d_in[4];
    const float* W_end   = (const float*)d_in[5];
    const float* b_end   = (const float*)d_in[6];
    const float* W_s1    = (const float*)d_in[7];
    const float* b_s1    = (const float*)d_in[8];
    const float* W_s2    = (const float*)d_in[9];
    const float* b_s2    = (const float*)d_in[10];
    const float* W_inj   = (const float*)d_in[11];
    const float* b_inj   = (const float*)d_in[12];
    const float* W_sec   = (const float*)d_in[13];
    const float* b_sec   = (const float*)d_in[14];
    const float* W_pred  = (const float*)d_in[15];
    const float* b_pred  = (const float*)d_in[16];
    float* out = (float*)d_out;

    float* AE         = (float*)d_ws;
    float* scores     = AE + (size_t)BB * T * 512;
    int*   s_idx      = (int*)(scores + (size_t)BB * NSPAN);
    int*   e_idx      = s_idx + NSPAN;
    int*   top_idx    = e_idx + NSPAN;
    float* top_scores = (float*)(top_idx + BB * KTOP);
    float* injv       = top_scores + BB * KTOP;
    unsigned short* Wpk = (unsigned short*)(injv + BB * H);
    int*   shortlist  = (int*)(Wpk + 65536);
    int*   slcnt      = shortlist + BB * SCAP;

    build_idx_kernel<<<1, 128, 0, stream>>>(s_idx, e_idx);
    proj_kernel<<<dim3(128, 4), 256, 0, stream>>>(inputs, W_start, b_start, W_end, b_end, AE);
    wpack_kernel<<<256, 256, 0, stream>>>(W_s1, Wpk);
    approx_kernel<<<dim3(65, BB), 256, 0, stream>>>(AE, Wpk, b_s1, W_s2, b_s2,
                                                    s_idx, e_idx, imask, scores);
    select_kernel<<<BB, 256, 0, stream>>>(scores, shortlist, slcnt);
    exact_kernel<<<dim3(16, BB), 256, 0, stream>>>(AE, W_s1, b_s1, W_s2, b_s2,
                                                   s_idx, e_idx, shortlist, slcnt, scores);
    inj_kernel<<<BB, 256, 0, stream>>>(tie, W_inj, b_inj, injv);
    topk_kernel<<<BB, 256, 0, stream>>>(scores, top_idx, top_scores);
    final_kernel<<<BB * 4, 256, 0, stream>>>(AE, s_idx, e_idx, imask, top_idx, top_scores,
                                             injv, W_sec, b_sec, W_pred, b_pred, out);
}

// Round 4
// 617.990 us; speedup vs baseline: 2.5658x; 1.0093x over previous
//
#include <hip/hip_runtime.h>
#include <hip/hip_bf16.h>
#include <math.h>

#define BB 64
#define T 128
#define DD 768
#define H 256
#define JJ 128
#define NSPAN 8256
#define KTOP 256
#define SCAP 1024
#define MARGIN 0.03f

typedef __attribute__((ext_vector_type(8))) short bf16x8;
typedef __attribute__((ext_vector_type(4))) float f32x4;

__device__ inline unsigned short bfrne(float x) {
    unsigned u = __float_as_uint(x);
    return (unsigned short)((u + 0x7FFFu + ((u >> 16) & 1u)) >> 16);
}

__device__ inline unsigned pk2(float x, float y) {
    float2 f; f.x = x; f.y = y;
    __hip_bfloat162 h = __float22bfloat162_rn(f);
    return *reinterpret_cast<unsigned*>(&h);
}

// ---------------------------------------------------------------------------
// Kernel 0: triu span index tables (start-major, matches jnp.triu_indices)
// ---------------------------------------------------------------------------
__global__ void build_idx_kernel(int* s_idx, int* e_idx) {
    int s = threadIdx.x;
    if (s < T) {
        int start = s * T - (s * (s - 1)) / 2;
        int len = T - s;
        for (int i = 0; i < len; ++i) {
            s_idx[start + i] = s;
            e_idx[start + i] = s + i;
        }
    }
}

// ---------------------------------------------------------------------------
// Kernel 1: proj GEMM (unchanged this round)
// ---------------------------------------------------------------------------
__global__ __launch_bounds__(256) void proj_kernel(
    const float* __restrict__ X,
    const float* __restrict__ Wa, const float* __restrict__ ba,
    const float* __restrict__ Wb, const float* __restrict__ bb,
    float* __restrict__ AE)
{
    const int m0 = blockIdx.x * 64;
    const int c0 = blockIdx.y * 128;
    const float* W;
    const float* bias;
    int wc0;
    if (c0 < 256) { W = Wa; bias = ba; wc0 = c0; }
    else          { W = Wb; bias = bb; wc0 = c0 - 256; }

    __shared__ float Xs[64][20];
    __shared__ float Ws[16][132];

    const int t  = threadIdx.x;
    const int tx = t & 31;
    const int ty = t >> 5;

    float acc[8][4];
#pragma unroll
    for (int i = 0; i < 8; ++i)
#pragma unroll
        for (int j = 0; j < 4; ++j) acc[i][j] = 0.f;

    for (int kk = 0; kk < DD; kk += 16) {
        __syncthreads();
        {
            int row = t >> 2, k4 = (t & 3) * 4;
            float4 v = *(const float4*)&X[(size_t)(m0 + row) * DD + kk + k4];
            *(float4*)&Xs[row][k4] = v;
        }
        {
            int row = t >> 4, c8 = (t & 15) * 8;
            float4 w0 = *(const float4*)&W[(size_t)(kk + row) * 256 + wc0 + c8];
            float4 w1 = *(const float4*)&W[(size_t)(kk + row) * 256 + wc0 + c8 + 4];
            *(float4*)&Ws[row][c8]     = w0;
            *(float4*)&Ws[row][c8 + 4] = w1;
        }
        __syncthreads();
#pragma unroll
        for (int k4 = 0; k4 < 16; k4 += 4) {
            float w[4][4];
#pragma unroll
            for (int kq = 0; kq < 4; ++kq) {
                float4 wv = *(const float4*)&Ws[k4 + kq][tx * 4];
                w[kq][0] = wv.x; w[kq][1] = wv.y; w[kq][2] = wv.z; w[kq][3] = wv.w;
            }
#pragma unroll
            for (int i = 0; i < 8; ++i) {
                float4 xv = *(const float4*)&Xs[ty * 8 + i][k4];
                float xq[4] = {xv.x, xv.y, xv.z, xv.w};
#pragma unroll
                for (int kq = 0; kq < 4; ++kq)
#pragma unroll
                    for (int j = 0; j < 4; ++j)
                        acc[i][j] = fmaf(xq[kq], w[kq][j], acc[i][j]);
            }
        }
    }
    float bj[4];
#pragma unroll
    for (int j = 0; j < 4; ++j) bj[j] = bias[wc0 + tx * 4 + j];
#pragma unroll
    for (int i = 0; i < 8; ++i) {
        float4 o;
        o.x = acc[i][0] + bj[0]; o.y = acc[i][1] + bj[1];
        o.z = acc[i][2] + bj[2]; o.w = acc[i][3] + bj[3];
        *(float4*)&AE[(size_t)(m0 + ty * 8 + i) * 512 + c0 + tx * 4] = o;
    }
}

// ---------------------------------------------------------------------------
// Kernel 1b: pack W_s1 into bf16 MFMA B-fragment layout.
// ---------------------------------------------------------------------------
__global__ __launch_bounds__(256) void wpack_kernel(
    const float* __restrict__ W1, unsigned short* __restrict__ Wpk)
{
    int idx = blockIdx.x * 256 + threadIdx.x;   // 65536 total
    int j  = idx & 7;
    int l  = (idx >> 3) & 63;
    int kc = (idx >> 9) & 7;
    int ct = idx >> 12;
    int k = kc * 32 + (l >> 4) * 8 + j;
    int n = ct * 16 + (l & 15);
    Wpk[idx] = bfrne(W1[k * 256 + n]);
}

// ---------------------------------------------------------------------------
// Kernel 2: approximate span scorer via bf16 MFMA 16x16x32.
// Fragment-contiguous LDS (conflict-free), all B frags of the wave's 4 ct
// tiles preloaded to registers (A frags read once), packed bf16 cvt.
// ---------------------------------------------------------------------------
__global__ __launch_bounds__(256, 2) void approx_kernel(
    const float* __restrict__ AE,
    const unsigned short* __restrict__ Wpk,
    const float* __restrict__ bs1, const float* __restrict__ Ws2,
    const float* __restrict__ bs2g,
    const int* __restrict__ s_idx, const int* __restrict__ e_idx,
    const int* __restrict__ maskp,
    float* __restrict__ scores)
{
    const int b  = blockIdx.y;
    const int n0 = blockIdx.x * 128;

    __shared__ unsigned short rshf[32768];     // frag layout: [sp8][kc8][lane64][8]
    __shared__ float pslice[4][128];
    __shared__ int   ss[128], se[128];
    __shared__ float msk[128];

    const int t    = threadIdx.x;
    const int w    = t >> 6;
    const int lane = t & 63;
    const int lrow16 = lane & 15;

    // start B-fragment loads early (independent of LDS staging)
    bf16x8 bfr[4][8];
#pragma unroll
    for (int c = 0; c < 4; ++c)
#pragma unroll
        for (int kc = 0; kc < 8; ++kc)
            bfr[c][kc] = *(const bf16x8*)&Wpk[((((w * 4 + c) * 8 + kc) * 64) + lane) * 8];
    float b1c[4], w2c[4];
#pragma unroll
    for (int c = 0; c < 4; ++c) {
        int col = (w * 4 + c) * 16 + lrow16;
        b1c[c] = bs1[col];
        w2c[c] = Ws2[col];
    }

    if (t < 128) {
        int n = n0 + t;
        int s = 0, e = 0;
        float mv = 0.f;
        if (n < NSPAN) {
            s = s_idx[n]; e = e_idx[n];
            mv = (maskp[b * T + s] != 0 && maskp[b * T + e] != 0) ? 1.f : 0.f;
        }
        ss[t] = s; se[t] = e; msk[t] = mv;
    }
    __syncthreads();

    const float* Abase = AE + (size_t)b * T * 512;
    {   // stage relu(A[s]+E[e]) as bf16 directly into fragment layout
        const int sp    = t >> 1;
        const int khalf = t & 1;
        const int tile  = sp >> 4;
        const int lrow  = sp & 15;
        const float* Ar = Abase + (size_t)ss[sp] * 512 + khalf * 128;
        const float* Er = Abase + (size_t)se[sp] * 512 + 256 + khalf * 128;
#pragma unroll
        for (int i = 0; i < 16; ++i) {
            float4 a0 = *(const float4*)&Ar[i * 8];
            float4 a1 = *(const float4*)&Ar[i * 8 + 4];
            float4 e0 = *(const float4*)&Er[i * 8];
            float4 e1 = *(const float4*)&Er[i * 8 + 4];
            uint4 v;
            v.x = pk2(fmaxf(a0.x + e0.x, 0.f), fmaxf(a0.y + e0.y, 0.f));
            v.y = pk2(fmaxf(a0.z + e0.z, 0.f), fmaxf(a0.w + e0.w, 0.f));
            v.z = pk2(fmaxf(a1.x + e1.x, 0.f), fmaxf(a1.y + e1.y, 0.f));
            v.w = pk2(fmaxf(a1.z + e1.z, 0.f), fmaxf(a1.w + e1.w, 0.f));
            int kc = khalf * 4 + (i >> 2);
            int q  = i & 3;
            *(uint4*)&rshf[((tile * 8 + kc) * 64 + q * 16 + lrow) * 8] = v;
        }
    }
    __syncthreads();

    const int quad = lane >> 4;

    float pp[8][4];
#pragma unroll
    for (int sp = 0; sp < 8; ++sp)
#pragma unroll
        for (int r = 0; r < 4; ++r) pp[sp][r] = 0.f;

#pragma unroll
    for (int sp = 0; sp < 8; ++sp) {
        bf16x8 afr[8];
#pragma unroll
        for (int kc = 0; kc < 8; ++kc)
            afr[kc] = *(const bf16x8*)&rshf[(sp * 8 + kc) * 512 + lane * 8];
        f32x4 acc[4];
#pragma unroll
        for (int c = 0; c < 4; ++c) acc[c] = (f32x4){0.f, 0.f, 0.f, 0.f};
#pragma unroll
        for (int kc = 0; kc < 8; ++kc)
#pragma unroll
            for (int c = 0; c < 4; ++c)
                acc[c] = __builtin_amdgcn_mfma_f32_16x16x32_bf16(afr[kc], bfr[c][kc], acc[c], 0, 0, 0);
#pragma unroll
        for (int c = 0; c < 4; ++c)
#pragma unroll
            for (int r = 0; r < 4; ++r)
                pp[sp][r] += fmaxf(acc[c][r] + b1c[c], 0.f) * w2c[c];
    }

    // reduce over the 16-lane col dimension
#pragma unroll
    for (int off = 1; off < 16; off <<= 1)
#pragma unroll
        for (int sp = 0; sp < 8; ++sp)
#pragma unroll
            for (int r = 0; r < 4; ++r)
                pp[sp][r] += __shfl_xor(pp[sp][r], off, 16);
    if (lrow16 == 0) {
#pragma unroll
        for (int sp = 0; sp < 8; ++sp) {
            float4 v;
            v.x = pp[sp][0]; v.y = pp[sp][1]; v.z = pp[sp][2]; v.w = pp[sp][3];
            *(float4*)&pslice[w][sp * 16 + quad * 4] = v;
        }
    }
    __syncthreads();
    if (t < 128) {
        int n = n0 + t;
        if (n < NSPAN) {
            float sc = pslice[0][t] + pslice[1][t] + pslice[2][t] + pslice[3][t] + bs2g[0];
            scores[(size_t)b * NSPAN + n] = (msk[t] > 0.f) ? sc : -INFINITY;
        }
    }
}

// ---------------------------------------------------------------------------
// Kernel 3: per-batch shortlist select (radix-select kth, keep >= kth-MARGIN)
// ---------------------------------------------------------------------------
__global__ __launch_bounds__(256) void select_kernel(
    const float* __restrict__ scores,
    int* __restrict__ shortlist, int* __restrict__ slcnt)
{
    const int b = blockIdx.x;
    const int t = threadIdx.x;
    __shared__ unsigned su[NSPAN];
    __shared__ int red[4];
    __shared__ int wave_keep[4];

    const float* sc = scores + (size_t)b * NSPAN;
    for (int i = t; i < NSPAN; i += 256) {
        unsigned ub = __float_as_uint(sc[i]);
        su[i] = (ub & 0x80000000u) ? ~ub : (ub | 0x80000000u);
    }
    __syncthreads();

    unsigned prefix = 0;
    int remaining = KTOP;
    const int wid = t >> 6, lane = t & 63;
    for (int bit = 31; bit >= 0; --bit) {
        unsigned pat = (prefix >> bit) | 1u;
        int cnt = 0;
        for (int i = t; i < NSPAN; i += 256)
            cnt += ((su[i] >> bit) == pat) ? 1 : 0;
#pragma unroll
        for (int off = 32; off > 0; off >>= 1)
            cnt += __shfl_down(cnt, off, 64);
        if (lane == 0) red[wid] = cnt;
        __syncthreads();
        int c = red[0] + red[1] + red[2] + red[3];
        if (c >= remaining) prefix |= (1u << bit);
        else remaining -= c;
        __syncthreads();
    }
    unsigned ub = (prefix & 0x80000000u) ? (prefix & 0x7FFFFFFFu) : ~prefix;
    float kthf = __uint_as_float(ub);
    float tau = kthf - MARGIN;
    unsigned tb = __float_as_uint(tau);
    unsigned ktau = (tb & 0x80000000u) ? ~tb : (tb | 0x80000000u);

    int base = 0;
    const unsigned long long ltmask = (1ull << lane) - 1ull;
    for (int c0 = 0; c0 < NSPAN; c0 += 256) {
        int n = c0 + t;
        bool keep = (n < NSPAN) && (su[n] >= ktau);
        unsigned long long bk = __ballot(keep);
        int before = __popcll(bk & ltmask);
        if (lane == 0) wave_keep[wid] = __popcll(bk);
        __syncthreads();
        int kb = base;
        for (int wv = 0; wv < wid; ++wv) kb += wave_keep[wv];
        if (keep) {
            int pos = kb + before;
            if (pos < SCAP) shortlist[b * SCAP + pos] = n;
        }
        for (int wv = 0; wv < 4; ++wv) base += wave_keep[wv];
        __syncthreads();
    }
    if (t == 0) slcnt[b] = base < SCAP ? base : SCAP;
}

// ---------------------------------------------------------------------------
// Kernel 4: exact fp32 scorer on the shortlist (unchanged)
// ---------------------------------------------------------------------------
__global__ __launch_bounds__(256) void exact_kernel(
    const float* __restrict__ AE,
    const float* __restrict__ Ws1, const float* __restrict__ bs1,
    const float* __restrict__ Ws2, const float* __restrict__ bs2g,
    const int* __restrict__ s_idx, const int* __restrict__ e_idx,
    const int* __restrict__ shortlist, const int* __restrict__ slcnt,
    float* __restrict__ scores)
{
    const int b  = blockIdx.y;
    const int n0 = blockIdx.x * 64;
    const int cntb = slcnt[b];
    if (n0 >= cntb) return;

    __shared__ float rsh[64][36];
    __shared__ float Ws[32][260];
    __shared__ int   ss[64], se[64], nn[64];

    const int t = threadIdx.x;
    if (t < 64) {
        int row = n0 + t;
        int n = 0;
        if (row < cntb) n = shortlist[b * SCAP + row];
        nn[t] = (row < cntb) ? n : -1;
        ss[t] = s_idx[n]; se[t] = e_idx[n];
    }
    __syncthreads();

    const int tx = t & 31;
    const int ty = t >> 5;
    float acc[8][8];
#pragma unroll
    for (int i = 0; i < 8; ++i)
#pragma unroll
        for (int j = 0; j < 8; ++j) acc[i][j] = 0.f;

    const float* Abase = AE + (size_t)b * T * 512;

    for (int kk = 0; kk < 256; kk += 32) {
        __syncthreads();
        {
            int c4 = (t & 63) * 4, r0 = t >> 6;
#pragma unroll
            for (int r8 = 0; r8 < 8; ++r8) {
                int row = r0 + r8 * 4;
                *(float4*)&Ws[row][c4] =
                    *(const float4*)&Ws1[(size_t)(kk + row) * 256 + c4];
            }
        }
        {
            int sp = t >> 2, k8 = (t & 3) * 8;
            const float* Ar = Abase + (size_t)ss[sp] * 512 + kk + k8;
            const float* Er = Abase + (size_t)se[sp] * 512 + 256 + kk + k8;
#pragma unroll
            for (int q = 0; q < 2; ++q) {
                float4 a = *(const float4*)&Ar[q * 4];
                float4 e = *(const float4*)&Er[q * 4];
                float4 v;
                v.x = fmaxf(a.x + e.x, 0.f); v.y = fmaxf(a.y + e.y, 0.f);
                v.z = fmaxf(a.z + e.z, 0.f); v.w = fmaxf(a.w + e.w, 0.f);
                *(float4*)&rsh[sp][k8 + q * 4] = v;
            }
        }
        __syncthreads();
#pragma unroll
        for (int k4 = 0; k4 < 32; k4 += 4) {
            float w[4][8];
#pragma unroll
            for (int kq = 0; kq < 4; ++kq) {
                float4 w0 = *(const float4*)&Ws[k4 + kq][tx * 4];
                float4 w1 = *(const float4*)&Ws[k4 + kq][128 + tx * 4];
                w[kq][0] = w0.x; w[kq][1] = w0.y; w[kq][2] = w0.z; w[kq][3] = w0.w;
                w[kq][4] = w1.x; w[kq][5] = w1.y; w[kq][6] = w1.z; w[kq][7] = w1.w;
            }
#pragma unroll
            for (int i = 0; i < 8; ++i) {
                float4 rv = *(const float4*)&rsh[ty * 8 + i][k4];
                float rq[4] = {rv.x, rv.y, rv.z, rv.w};
#pragma unroll
                for (int kq = 0; kq < 4; ++kq)
#pragma unroll
                    for (int j = 0; j < 8; ++j)
                        acc[i][j] = fmaf(rq[kq], w[kq][j], acc[i][j]);
            }
        }
    }

    float b1[8], w2[8];
#pragma unroll
    for (int j = 0; j < 8; ++j) {
        int c = (j < 4) ? (tx * 4 + j) : (128 + tx * 4 + j - 4);
        b1[j] = bs1[c];
        w2[j] = Ws2[c];
    }
    const float bs2v = bs2g[0];
#pragma unroll
    for (int i = 0; i < 8; ++i) {
        int r = ty * 8 + i;
        float p = 0.f;
#pragma unroll
        for (int j = 0; j < 8; ++j)
            p += fmaxf(acc[i][j] + b1[j], 0.f) * w2[j];
#pragma unroll
        for (int off = 16; off > 0; off >>= 1)
            p += __shfl_down(p, off, 32);
        if (tx == 0) {
            int n = nn[r];
            if (n >= 0)
                scores[(size_t)b * NSPAN + n] = p + bs2v;
        }
    }
}

// ---------------------------------------------------------------------------
// Kernel 5: injection projection
// ---------------------------------------------------------------------------
__global__ __launch_bounds__(256) void inj_kernel(
    const float* __restrict__ tie, const float* __restrict__ Winj,
    const float* __restrict__ binj, float* __restrict__ inj)
{
    int b = blockIdx.x;
    int h = threadIdx.x;
    __shared__ float tb[JJ];
    if (threadIdx.x < JJ) tb[threadIdx.x] = tie[b * JJ + threadIdx.x];
    __syncthreads();
    float a = binj[h];
    for (int j = 0; j < JJ; ++j)
        a = fmaf(tb[j], Winj[j * H + h], a);
    inj[b * H + h] = a;
}

// ---------------------------------------------------------------------------
// Kernel 6: per-batch top-K, jax tie-break, ascending output
// ---------------------------------------------------------------------------
__global__ __launch_bounds__(256) void topk_kernel(
    const float* __restrict__ scores,
    int* __restrict__ top_idx, float* __restrict__ top_scores)
{
    const int b = blockIdx.x;
    const int t = threadIdx.x;
    __shared__ unsigned su[NSPAN];
    __shared__ int red[4];
    __shared__ int wave_eq[4], wave_keep[4];

    const float* sc = scores + (size_t)b * NSPAN;
    for (int i = t; i < NSPAN; i += 256) {
        unsigned ub = __float_as_uint(sc[i]);
        su[i] = (ub & 0x80000000u) ? ~ub : (ub | 0x80000000u);
    }
    __syncthreads();

    unsigned prefix = 0;
    int remaining = KTOP;
    const int wid = t >> 6, lane = t & 63;
    for (int bit = 31; bit >= 0; --bit) {
        unsigned pat = (prefix >> bit) | 1u;
        int cnt = 0;
        for (int i = t; i < NSPAN; i += 256)
            cnt += ((su[i] >> bit) == pat) ? 1 : 0;
#pragma unroll
        for (int off = 32; off > 0; off >>= 1)
            cnt += __shfl_down(cnt, off, 64);
        if (lane == 0) red[wid] = cnt;
        __syncthreads();
        int c = red[0] + red[1] + red[2] + red[3];
        if (c >= remaining) prefix |= (1u << bit);
        else remaining -= c;
        __syncthreads();
    }
    const unsigned v = prefix;
    const int need_eq = remaining;

    int base_eq = 0, base_keep = 0;
    const unsigned long long ltmask = (1ull << lane) - 1ull;
    for (int c0 = 0; c0 < NSPAN; c0 += 256) {
        int n = c0 + t;
        bool valid = n < NSPAN;
        unsigned u = valid ? su[n] : 0u;
        bool eq = valid && (u == v);
        bool gt = valid && (u > v);
        unsigned long long beq = __ballot(eq);
        int eq_before = __popcll(beq & ltmask);
        if (lane == 0) wave_eq[wid] = __popcll(beq);
        __syncthreads();
        int eqb = base_eq;
        for (int w = 0; w < wid; ++w) eqb += wave_eq[w];
        int eq_rank = eqb + eq_before;
        bool keep = gt || (eq && (eq_rank < need_eq));
        unsigned long long bk = __ballot(keep);
        int keep_before = __popcll(bk & ltmask);
        if (lane == 0) wave_keep[wid] = __popcll(bk);
        __syncthreads();
        int kb = base_keep;
        for (int w = 0; w < wid; ++w) kb += wave_keep[w];
        if (keep) {
            int pos = kb + keep_before;
            top_idx[b * KTOP + pos] = n;
            unsigned fb = (u & 0x80000000u) ? (u & 0x7FFFFFFFu) : ~u;
            float f = __uint_as_float(fb);
            top_scores[b * KTOP + pos] = isinf(f) ? -1.0f : f;
        }
        for (int w = 0; w < 4; ++w) { base_eq += wave_eq[w]; base_keep += wave_keep[w]; }
        __syncthreads();
    }
}

// ---------------------------------------------------------------------------
// Kernel 7: final head (unchanged)
// ---------------------------------------------------------------------------
__global__ __launch_bounds__(256) void final_kernel(
    const float* __restrict__ AE,
    const int* __restrict__ s_idx, const int* __restrict__ e_idx,
    const int* __restrict__ maskp,
    const int* __restrict__ top_idx, const float* __restrict__ top_scores,
    const float* __restrict__ injv,
    const float* __restrict__ Wsec, const float* __restrict__ bsec,
    const float* __restrict__ Wpred, const float* __restrict__ bpredg,
    float* __restrict__ out)
{
    const int b = blockIdx.x >> 2;
    const int k0 = (blockIdx.x & 3) * 64;

    __shared__ float sh[64][36];
    __shared__ float Ws[32][260];
    __shared__ int ss[64], se[64];
    __shared__ float msk[64], tsc[64];

    const int t = threadIdx.x;
    if (t < 64) {
        int kidx = k0 + t;
        int n = top_idx[b * KTOP + kidx];
        int s = s_idx[n], e = e_idx[n];
        ss[t] = s; se[t] = e;
        msk[t] = (maskp[b * T + s] != 0 && maskp[b * T + e] != 0) ? 1.f : 0.f;
        tsc[t] = top_scores[b * KTOP + kidx];
    }
    __syncthreads();

    const int tx = t & 31;
    const int ty = t >> 5;
    float acc[8][8];
#pragma unroll
    for (int i = 0; i < 8; ++i)
#pragma unroll
        for (int j = 0; j < 8; ++j) acc[i][j] = 0.f;

    const float* Abase = AE + (size_t)b * T * 512;

    for (int kk = 0; kk < 256; kk += 32) {
        __syncthreads();
        {
            int c4 = (t & 63) * 4, r0 = t >> 6;
#pragma unroll
            for (int r8 = 0; r8 < 8; ++r8) {
                int row = r0 + r8 * 4;
                *(float4*)&Ws[row][c4] =
                    *(const float4*)&Wsec[(size_t)(kk + row) * 256 + c4];
            }
        }
        {
            int sp = t >> 2, k8 = (t & 3) * 8;
            const float* Ar = Abase + (size_t)ss[sp] * 512 + kk + k8;
            const float* Er = Abase + (size_t)se[sp] * 512 + 256 + kk + k8;
#pragma unroll
            for (int q = 0; q < 2; ++q) {
                float4 a = *(const float4*)&Ar[q * 4];
                float4 e = *(const float4*)&Er[q * 4];
                float4 v;
                v.x = a.x + e.x; v.y = a.y + e.y; v.z = a.z + e.z; v.w = a.w + e.w;
                *(float4*)&sh[sp][k8 + q * 4] = v;
            }
        }
        __syncthreads();
#pragma unroll
        for (int k4 = 0; k4 < 32; k4 += 4) {
            float w[4][8];
#pragma unroll
            for (int kq = 0; kq < 4; ++kq) {
                float4 w0 = *(const float4*)&Ws[k4 + kq][tx * 4];
                float4 w1 = *(const float4*)&Ws[k4 + kq][128 + tx * 4];
                w[kq][0] = w0.x; w[kq][1] = w0.y; w[kq][2] = w0.z; w[kq][3] = w0.w;
                w[kq][4] = w1.x; w[kq][5] = w1.y; w[kq][6] = w1.z; w[kq][7] = w1.w;
            }
#pragma unroll
            for (int i = 0; i < 8; ++i) {
                float4 rv = *(const float4*)&sh[ty * 8 + i][k4];
                float rq[4] = {rv.x, rv.y, rv.z, rv.w};
#pragma unroll
                for (int kq = 0; kq < 4; ++kq)
#pragma unroll
                    for (int j = 0; j < 8; ++j)
                        acc[i][j] = fmaf(rq[kq], w[kq][j], acc[i][j]);
            }
        }
    }

    float bsec_r[8], wpred_r[8], injr[8];
#pragma unroll
    for (int j = 0; j < 8; ++j) {
        int c = (j < 4) ? (tx * 4 + j) : (128 + tx * 4 + j - 4);
        bsec_r[j] = bsec[c];
        wpred_r[j] = Wpred[c];
        injr[j] = injv[b * H + c];
    }
    const float bp = bpredg[0];
#pragma unroll
    for (int i = 0; i < 8; ++i) {
        int r = ty * 8 + i;
        float p = 0.f;
#pragma unroll
        for (int j = 0; j < 8; ++j) {
            float sec = acc[i][j] + bsec_r[j];
            p += fmaxf(injr[j] + sec, 0.f) * wpred_r[j];
        }
#pragma unroll
        for (int off = 16; off > 0; off >>= 1)
            p += __shfl_down(p, off, 32);
        if (tx == 0) {
            float logit = p + bp + tsc[r];
            float prob = (1.f / (1.f + expf(-logit))) * msk[r];
            out[b * KTOP + k0 + r] = prob;
        }
    }
}

// ---------------------------------------------------------------------------
extern "C" void kernel_launch(void* const* d_in, const int* in_sizes, int n_in,
                              void* d_out, int out_size, void* d_ws, size_t ws_size,
                              hipStream_t stream) {
    const float* inputs  = (const float*)d_in[0];
    const int*   imask   = (const int*)d_in[1];
    const float* tie     = (const float*)d_in[2];
    const float* W_start = (const float*)d_in[3];
    const float* b_start = (const float*)d_in[4];
    const float* W_end   = (const float*)d_in[5];
    const float* b_end   = (const float*)d_in[6];
    const float* W_s1    = (const float*)d_in[7];
    const float* b_s1    = (const float*)d_in[8];
    const float* W_s2    = (const float*)d_in[9];
    const float* b_s2    = (const float*)d_in[10];
    const float* W_inj   = (const float*)d_in[11];
    const float* b_inj   = (const float*)d_in[12];
    const float* W_sec   = (const float*)d_in[13];
    const float* b_sec   = (const float*)d_in[14];
    const float* W_pred  = (const float*)d_in[15];
    const float* b_pred  = (const float*)d_in[16];
    float* out = (float*)d_out;

    float* AE         = (float*)d_ws;
    float* scores     = AE + (size_t)BB * T * 512;
    int*   s_idx      = (int*)(scores + (size_t)BB * NSPAN);
    int*   e_idx      = s_idx + NSPAN;
    int*   top_idx    = e_idx + NSPAN;
    float* top_scores = (float*)(top_idx + BB * KTOP);
    float* injv       = top_scores + BB * KTOP;
    unsigned short* Wpk = (unsigned short*)(injv + BB * H);
    int*   shortlist  = (int*)(Wpk + 65536);
    int*   slcnt      = shortlist + BB * SCAP;

    build_idx_kernel<<<1, 128, 0, stream>>>(s_idx, e_idx);
    proj_kernel<<<dim3(128, 4), 256, 0, stream>>>(inputs, W_start, b_start, W_end, b_end, AE);
    wpack_kernel<<<256, 256, 0, stream>>>(W_s1, Wpk);
    approx_kernel<<<dim3(65, BB), 256, 0, stream>>>(AE, Wpk, b_s1, W_s2, b_s2,
                                                    s_idx, e_idx, imask, scores);
    select_kernel<<<BB, 256, 0, stream>>>(scores, shortlist, slcnt);
    exact_kernel<<<dim3(16, BB), 256, 0, stream>>>(AE, W_s1, b_s1, W_s2, b_s2,
                                                   s_idx, e_idx, shortlist, slcnt, scores);
    inj_kernel<<<BB, 256, 0, stream>>>(tie, W_inj, b_inj, injv);
    topk_kernel<<<BB, 256, 0, stream>>>(scores, top_idx, top_scores);
    final_kernel<<<BB * 4, 256, 0, stream>>>(AE, s_idx, e_idx, imask, top_idx, top_scores,
                                             injv, W_sec, b_sec, W_pred, b_pred, out);
}

// Round 5
// 563.529 us; speedup vs baseline: 2.8138x; 1.0966x over previous
//
#include <hip/hip_runtime.h>
#include <hip/hip_bf16.h>
#include <math.h>

#define BB 64
#define T 128
#define DD 768
#define H 256
#define JJ 128
#define NSPAN 8256
#define KTOP 256
#define SCAP 1024
#define MARGIN 0.03f

typedef __attribute__((ext_vector_type(8))) short bf16x8;
typedef __attribute__((ext_vector_type(4))) float f32x4;

__device__ inline unsigned short bfrne(float x) {
    unsigned u = __float_as_uint(x);
    return (unsigned short)((u + 0x7FFFu + ((u >> 16) & 1u)) >> 16);
}

__device__ inline unsigned pk2(float x, float y) {
    float2 f; f.x = x; f.y = y;
    __hip_bfloat162 h = __float22bfloat162_rn(f);
    return *reinterpret_cast<unsigned*>(&h);
}

// ---------------------------------------------------------------------------
// Kernel 0: triu span index tables (start-major, matches jnp.triu_indices)
// ---------------------------------------------------------------------------
__global__ void build_idx_kernel(int* s_idx, int* e_idx) {
    int s = threadIdx.x;
    if (s < T) {
        int start = s * T - (s * (s - 1)) / 2;
        int len = T - s;
        for (int i = 0; i < len; ++i) {
            s_idx[start + i] = s;
            e_idx[start + i] = s + i;
        }
    }
}

// ---------------------------------------------------------------------------
// Kernel 1: proj GEMM (unchanged this round)
// ---------------------------------------------------------------------------
__global__ __launch_bounds__(256) void proj_kernel(
    const float* __restrict__ X,
    const float* __restrict__ Wa, const float* __restrict__ ba,
    const float* __restrict__ Wb, const float* __restrict__ bb,
    float* __restrict__ AE)
{
    const int m0 = blockIdx.x * 64;
    const int c0 = blockIdx.y * 128;
    const float* W;
    const float* bias;
    int wc0;
    if (c0 < 256) { W = Wa; bias = ba; wc0 = c0; }
    else          { W = Wb; bias = bb; wc0 = c0 - 256; }

    __shared__ float Xs[64][20];
    __shared__ float Ws[16][132];

    const int t  = threadIdx.x;
    const int tx = t & 31;
    const int ty = t >> 5;

    float acc[8][4];
#pragma unroll
    for (int i = 0; i < 8; ++i)
#pragma unroll
        for (int j = 0; j < 4; ++j) acc[i][j] = 0.f;

    for (int kk = 0; kk < DD; kk += 16) {
        __syncthreads();
        {
            int row = t >> 2, k4 = (t & 3) * 4;
            float4 v = *(const float4*)&X[(size_t)(m0 + row) * DD + kk + k4];
            *(float4*)&Xs[row][k4] = v;
        }
        {
            int row = t >> 4, c8 = (t & 15) * 8;
            float4 w0 = *(const float4*)&W[(size_t)(kk + row) * 256 + wc0 + c8];
            float4 w1 = *(const float4*)&W[(size_t)(kk + row) * 256 + wc0 + c8 + 4];
            *(float4*)&Ws[row][c8]     = w0;
            *(float4*)&Ws[row][c8 + 4] = w1;
        }
        __syncthreads();
#pragma unroll
        for (int k4 = 0; k4 < 16; k4 += 4) {
            float w[4][4];
#pragma unroll
            for (int kq = 0; kq < 4; ++kq) {
                float4 wv = *(const float4*)&Ws[k4 + kq][tx * 4];
                w[kq][0] = wv.x; w[kq][1] = wv.y; w[kq][2] = wv.z; w[kq][3] = wv.w;
            }
#pragma unroll
            for (int i = 0; i < 8; ++i) {
                float4 xv = *(const float4*)&Xs[ty * 8 + i][k4];
                float xq[4] = {xv.x, xv.y, xv.z, xv.w};
#pragma unroll
                for (int kq = 0; kq < 4; ++kq)
#pragma unroll
                    for (int j = 0; j < 4; ++j)
                        acc[i][j] = fmaf(xq[kq], w[kq][j], acc[i][j]);
            }
        }
    }
    float bj[4];
#pragma unroll
    for (int j = 0; j < 4; ++j) bj[j] = bias[wc0 + tx * 4 + j];
#pragma unroll
    for (int i = 0; i < 8; ++i) {
        float4 o;
        o.x = acc[i][0] + bj[0]; o.y = acc[i][1] + bj[1];
        o.z = acc[i][2] + bj[2]; o.w = acc[i][3] + bj[3];
        *(float4*)&AE[(size_t)(m0 + ty * 8 + i) * 512 + c0 + tx * 4] = o;
    }
}

// ---------------------------------------------------------------------------
// Kernel 1b: pack W_s1 into bf16 MFMA B-fragment layout.
// ---------------------------------------------------------------------------
__global__ __launch_bounds__(256) void wpack_kernel(
    const float* __restrict__ W1, unsigned short* __restrict__ Wpk)
{
    int idx = blockIdx.x * 256 + threadIdx.x;   // 65536 total
    int j  = idx & 7;
    int l  = (idx >> 3) & 63;
    int kc = (idx >> 9) & 7;
    int ct = idx >> 12;
    int k = kc * 32 + (l >> 4) * 8 + j;
    int n = ct * 16 + (l & 15);
    Wpk[idx] = bfrne(W1[k * 256 + n]);
}

// ---------------------------------------------------------------------------
// Kernel 2: approximate span scorer via bf16 MFMA 16x16x32.
// Register-lean: 2 ct-passes (bfr[2][8]=64 VGPR), afr loaded per-kc,
// per-sp layer-2 fold reduced and accumulated straight into LDS pslice.
// No pp array, no spills.
// ---------------------------------------------------------------------------
__global__ __launch_bounds__(256, 2) void approx_kernel(
    const float* __restrict__ AE,
    const unsigned short* __restrict__ Wpk,
    const float* __restrict__ bs1, const float* __restrict__ Ws2,
    const float* __restrict__ bs2g,
    const int* __restrict__ s_idx, const int* __restrict__ e_idx,
    const int* __restrict__ maskp,
    float* __restrict__ scores)
{
    const int b  = blockIdx.y;
    const int n0 = blockIdx.x * 128;

    __shared__ unsigned short rshf[32768];     // frag layout: [sp8][kc8][lane64][8]
    __shared__ float pslice[4][128];
    __shared__ int   ss[128], se[128];
    __shared__ float msk[128];

    const int t      = threadIdx.x;
    const int w      = t >> 6;
    const int lane   = t & 63;
    const int lrow16 = lane & 15;
    const int quad   = lane >> 4;

    if (t < 128) {
        int n = n0 + t;
        int s = 0, e = 0;
        float mv = 0.f;
        if (n < NSPAN) {
            s = s_idx[n]; e = e_idx[n];
            mv = (maskp[b * T + s] != 0 && maskp[b * T + e] != 0) ? 1.f : 0.f;
        }
        ss[t] = s; se[t] = e; msk[t] = mv;
    }
    __syncthreads();

    const float* Abase = AE + (size_t)b * T * 512;
    {   // stage relu(A[s]+E[e]) as bf16 directly into fragment layout
        const int sp    = t >> 1;
        const int khalf = t & 1;
        const int tile  = sp >> 4;
        const int lrow  = sp & 15;
        const float* Ar = Abase + (size_t)ss[sp] * 512 + khalf * 128;
        const float* Er = Abase + (size_t)se[sp] * 512 + 256 + khalf * 128;
#pragma unroll
        for (int i = 0; i < 16; ++i) {
            float4 a0 = *(const float4*)&Ar[i * 8];
            float4 a1 = *(const float4*)&Ar[i * 8 + 4];
            float4 e0 = *(const float4*)&Er[i * 8];
            float4 e1 = *(const float4*)&Er[i * 8 + 4];
            uint4 v;
            v.x = pk2(fmaxf(a0.x + e0.x, 0.f), fmaxf(a0.y + e0.y, 0.f));
            v.y = pk2(fmaxf(a0.z + e0.z, 0.f), fmaxf(a0.w + e0.w, 0.f));
            v.z = pk2(fmaxf(a1.x + e1.x, 0.f), fmaxf(a1.y + e1.y, 0.f));
            v.w = pk2(fmaxf(a1.z + e1.z, 0.f), fmaxf(a1.w + e1.w, 0.f));
            int kc = khalf * 4 + (i >> 2);
            int q  = i & 3;
            *(uint4*)&rshf[((tile * 8 + kc) * 64 + q * 16 + lrow) * 8] = v;
        }
    }
    __syncthreads();

#pragma unroll
    for (int ctp = 0; ctp < 2; ++ctp) {
        const int ct0 = w * 4 + ctp * 2;
        // B fragments for this pass: 2 ct tiles x 8 kc = 64 VGPR
        bf16x8 bfr[2][8];
#pragma unroll
        for (int c = 0; c < 2; ++c)
#pragma unroll
            for (int kc = 0; kc < 8; ++kc)
                bfr[c][kc] = *(const bf16x8*)&Wpk[((((ct0 + c) * 8 + kc) * 64) + lane) * 8];
        float b1c[2], w2c[2];
#pragma unroll
        for (int c = 0; c < 2; ++c) {
            int col = (ct0 + c) * 16 + lrow16;
            b1c[c] = bs1[col];
            w2c[c] = Ws2[col];
        }

#pragma unroll
        for (int sp = 0; sp < 8; ++sp) {
            f32x4 acc0 = {0.f, 0.f, 0.f, 0.f};
            f32x4 acc1 = {0.f, 0.f, 0.f, 0.f};
#pragma unroll
            for (int kc = 0; kc < 8; ++kc) {
                bf16x8 a = *(const bf16x8*)&rshf[(sp * 8 + kc) * 512 + lane * 8];
                acc0 = __builtin_amdgcn_mfma_f32_16x16x32_bf16(a, bfr[0][kc], acc0, 0, 0, 0);
                acc1 = __builtin_amdgcn_mfma_f32_16x16x32_bf16(a, bfr[1][kc], acc1, 0, 0, 0);
            }
            float ps[4];
#pragma unroll
            for (int r = 0; r < 4; ++r)
                ps[r] = fmaxf(acc0[r] + b1c[0], 0.f) * w2c[0]
                      + fmaxf(acc1[r] + b1c[1], 0.f) * w2c[1];
#pragma unroll
            for (int off = 1; off < 16; off <<= 1)
#pragma unroll
                for (int r = 0; r < 4; ++r)
                    ps[r] += __shfl_xor(ps[r], off, 16);
            if (lrow16 == 0) {
                float* dst = &pslice[w][sp * 16 + quad * 4];
                if (ctp == 0) {
                    float4 v; v.x = ps[0]; v.y = ps[1]; v.z = ps[2]; v.w = ps[3];
                    *(float4*)dst = v;
                } else {
                    float4 v = *(const float4*)dst;
                    v.x += ps[0]; v.y += ps[1]; v.z += ps[2]; v.w += ps[3];
                    *(float4*)dst = v;
                }
            }
        }
    }
    __syncthreads();
    if (t < 128) {
        int n = n0 + t;
        if (n < NSPAN) {
            float sc = pslice[0][t] + pslice[1][t] + pslice[2][t] + pslice[3][t] + bs2g[0];
            scores[(size_t)b * NSPAN + n] = (msk[t] > 0.f) ? sc : -INFINITY;
        }
    }
}

// ---------------------------------------------------------------------------
// Kernel 3: per-batch shortlist select (radix-select kth, keep >= kth-MARGIN)
// ---------------------------------------------------------------------------
__global__ __launch_bounds__(256) void select_kernel(
    const float* __restrict__ scores,
    int* __restrict__ shortlist, int* __restrict__ slcnt)
{
    const int b = blockIdx.x;
    const int t = threadIdx.x;
    __shared__ unsigned su[NSPAN];
    __shared__ int red[4];
    __shared__ int wave_keep[4];

    const float* sc = scores + (size_t)b * NSPAN;
    for (int i = t; i < NSPAN; i += 256) {
        unsigned ub = __float_as_uint(sc[i]);
        su[i] = (ub & 0x80000000u) ? ~ub : (ub | 0x80000000u);
    }
    __syncthreads();

    unsigned prefix = 0;
    int remaining = KTOP;
    const int wid = t >> 6, lane = t & 63;
    for (int bit = 31; bit >= 0; --bit) {
        unsigned pat = (prefix >> bit) | 1u;
        int cnt = 0;
        for (int i = t; i < NSPAN; i += 256)
            cnt += ((su[i] >> bit) == pat) ? 1 : 0;
#pragma unroll
        for (int off = 32; off > 0; off >>= 1)
            cnt += __shfl_down(cnt, off, 64);
        if (lane == 0) red[wid] = cnt;
        __syncthreads();
        int c = red[0] + red[1] + red[2] + red[3];
        if (c >= remaining) prefix |= (1u << bit);
        else remaining -= c;
        __syncthreads();
    }
    unsigned ub = (prefix & 0x80000000u) ? (prefix & 0x7FFFFFFFu) : ~prefix;
    float kthf = __uint_as_float(ub);
    float tau = kthf - MARGIN;
    unsigned tb = __float_as_uint(tau);
    unsigned ktau = (tb & 0x80000000u) ? ~tb : (tb | 0x80000000u);

    int base = 0;
    const unsigned long long ltmask = (1ull << lane) - 1ull;
    for (int c0 = 0; c0 < NSPAN; c0 += 256) {
        int n = c0 + t;
        bool keep = (n < NSPAN) && (su[n] >= ktau);
        unsigned long long bk = __ballot(keep);
        int before = __popcll(bk & ltmask);
        if (lane == 0) wave_keep[wid] = __popcll(bk);
        __syncthreads();
        int kb = base;
        for (int wv = 0; wv < wid; ++wv) kb += wave_keep[wv];
        if (keep) {
            int pos = kb + before;
            if (pos < SCAP) shortlist[b * SCAP + pos] = n;
        }
        for (int wv = 0; wv < 4; ++wv) base += wave_keep[wv];
        __syncthreads();
    }
    if (t == 0) slcnt[b] = base < SCAP ? base : SCAP;
}

// ---------------------------------------------------------------------------
// Kernel 4: exact fp32 scorer on the shortlist (unchanged)
// ---------------------------------------------------------------------------
__global__ __launch_bounds__(256) void exact_kernel(
    const float* __restrict__ AE,
    const float* __restrict__ Ws1, const float* __restrict__ bs1,
    const float* __restrict__ Ws2, const float* __restrict__ bs2g,
    const int* __restrict__ s_idx, const int* __restrict__ e_idx,
    const int* __restrict__ shortlist, const int* __restrict__ slcnt,
    float* __restrict__ scores)
{
    const int b  = blockIdx.y;
    const int n0 = blockIdx.x * 64;
    const int cntb = slcnt[b];
    if (n0 >= cntb) return;

    __shared__ float rsh[64][36];
    __shared__ float Ws[32][260];
    __shared__ int   ss[64], se[64], nn[64];

    const int t = threadIdx.x;
    if (t < 64) {
        int row = n0 + t;
        int n = 0;
        if (row < cntb) n = shortlist[b * SCAP + row];
        nn[t] = (row < cntb) ? n : -1;
        ss[t] = s_idx[n]; se[t] = e_idx[n];
    }
    __syncthreads();

    const int tx = t & 31;
    const int ty = t >> 5;
    float acc[8][8];
#pragma unroll
    for (int i = 0; i < 8; ++i)
#pragma unroll
        for (int j = 0; j < 8; ++j) acc[i][j] = 0.f;

    const float* Abase = AE + (size_t)b * T * 512;

    for (int kk = 0; kk < 256; kk += 32) {
        __syncthreads();
        {
            int c4 = (t & 63) * 4, r0 = t >> 6;
#pragma unroll
            for (int r8 = 0; r8 < 8; ++r8) {
                int row = r0 + r8 * 4;
                *(float4*)&Ws[row][c4] =
                    *(const float4*)&Ws1[(size_t)(kk + row) * 256 + c4];
            }
        }
        {
            int sp = t >> 2, k8 = (t & 3) * 8;
            const float* Ar = Abase + (size_t)ss[sp] * 512 + kk + k8;
            const float* Er = Abase + (size_t)se[sp] * 512 + 256 + kk + k8;
#pragma unroll
            for (int q = 0; q < 2; ++q) {
                float4 a = *(const float4*)&Ar[q * 4];
                float4 e = *(const float4*)&Er[q * 4];
                float4 v;
                v.x = fmaxf(a.x + e.x, 0.f); v.y = fmaxf(a.y + e.y, 0.f);
                v.z = fmaxf(a.z + e.z, 0.f); v.w = fmaxf(a.w + e.w, 0.f);
                *(float4*)&rsh[sp][k8 + q * 4] = v;
            }
        }
        __syncthreads();
#pragma unroll
        for (int k4 = 0; k4 < 32; k4 += 4) {
            float w[4][8];
#pragma unroll
            for (int kq = 0; kq < 4; ++kq) {
                float4 w0 = *(const float4*)&Ws[k4 + kq][tx * 4];
                float4 w1 = *(const float4*)&Ws[k4 + kq][128 + tx * 4];
                w[kq][0] = w0.x; w[kq][1] = w0.y; w[kq][2] = w0.z; w[kq][3] = w0.w;
                w[kq][4] = w1.x; w[kq][5] = w1.y; w[kq][6] = w1.z; w[kq][7] = w1.w;
            }
#pragma unroll
            for (int i = 0; i < 8; ++i) {
                float4 rv = *(const float4*)&rsh[ty * 8 + i][k4];
                float rq[4] = {rv.x, rv.y, rv.z, rv.w};
#pragma unroll
                for (int kq = 0; kq < 4; ++kq)
#pragma unroll
                    for (int j = 0; j < 8; ++j)
                        acc[i][j] = fmaf(rq[kq], w[kq][j], acc[i][j]);
            }
        }
    }

    float b1[8], w2[8];
#pragma unroll
    for (int j = 0; j < 8; ++j) {
        int c = (j < 4) ? (tx * 4 + j) : (128 + tx * 4 + j - 4);
        b1[j] = bs1[c];
        w2[j] = Ws2[c];
    }
    const float bs2v = bs2g[0];
#pragma unroll
    for (int i = 0; i < 8; ++i) {
        int r = ty * 8 + i;
        float p = 0.f;
#pragma unroll
        for (int j = 0; j < 8; ++j)
            p += fmaxf(acc[i][j] + b1[j], 0.f) * w2[j];
#pragma unroll
        for (int off = 16; off > 0; off >>= 1)
            p += __shfl_down(p, off, 32);
        if (tx == 0) {
            int n = nn[r];
            if (n >= 0)
                scores[(size_t)b * NSPAN + n] = p + bs2v;
        }
    }
}

// ---------------------------------------------------------------------------
// Kernel 5: injection projection
// ---------------------------------------------------------------------------
__global__ __launch_bounds__(256) void inj_kernel(
    const float* __restrict__ tie, const float* __restrict__ Winj,
    const float* __restrict__ binj, float* __restrict__ inj)
{
    int b = blockIdx.x;
    int h = threadIdx.x;
    __shared__ float tb[JJ];
    if (threadIdx.x < JJ) tb[threadIdx.x] = tie[b * JJ + threadIdx.x];
    __syncthreads();
    float a = binj[h];
    for (int j = 0; j < JJ; ++j)
        a = fmaf(tb[j], Winj[j * H + h], a);
    inj[b * H + h] = a;
}

// ---------------------------------------------------------------------------
// Kernel 6: per-batch top-K, jax tie-break, ascending output
// ---------------------------------------------------------------------------
__global__ __launch_bounds__(256) void topk_kernel(
    const float* __restrict__ scores,
    int* __restrict__ top_idx, float* __restrict__ top_scores)
{
    const int b = blockIdx.x;
    const int t = threadIdx.x;
    __shared__ unsigned su[NSPAN];
    __shared__ int red[4];
    __shared__ int wave_eq[4], wave_keep[4];

    const float* sc = scores + (size_t)b * NSPAN;
    for (int i = t; i < NSPAN; i += 256) {
        unsigned ub = __float_as_uint(sc[i]);
        su[i] = (ub & 0x80000000u) ? ~ub : (ub | 0x80000000u);
    }
    __syncthreads();

    unsigned prefix = 0;
    int remaining = KTOP;
    const int wid = t >> 6, lane = t & 63;
    for (int bit = 31; bit >= 0; --bit) {
        unsigned pat = (prefix >> bit) | 1u;
        int cnt = 0;
        for (int i = t; i < NSPAN; i += 256)
            cnt += ((su[i] >> bit) == pat) ? 1 : 0;
#pragma unroll
        for (int off = 32; off > 0; off >>= 1)
            cnt += __shfl_down(cnt, off, 64);
        if (lane == 0) red[wid] = cnt;
        __syncthreads();
        int c = red[0] + red[1] + red[2] + red[3];
        if (c >= remaining) prefix |= (1u << bit);
        else remaining -= c;
        __syncthreads();
    }
    const unsigned v = prefix;
    const int need_eq = remaining;

    int base_eq = 0, base_keep = 0;
    const unsigned long long ltmask = (1ull << lane) - 1ull;
    for (int c0 = 0; c0 < NSPAN; c0 += 256) {
        int n = c0 + t;
        bool valid = n < NSPAN;
        unsigned u = valid ? su[n] : 0u;
        bool eq = valid && (u == v);
        bool gt = valid && (u > v);
        unsigned long long beq = __ballot(eq);
        int eq_before = __popcll(beq & ltmask);
        if (lane == 0) wave_eq[wid] = __popcll(beq);
        __syncthreads();
        int eqb = base_eq;
        for (int w = 0; w < wid; ++w) eqb += wave_eq[w];
        int eq_rank = eqb + eq_before;
        bool keep = gt || (eq && (eq_rank < need_eq));
        unsigned long long bk = __ballot(keep);
        int keep_before = __popcll(bk & ltmask);
        if (lane == 0) wave_keep[wid] = __popcll(bk);
        __syncthreads();
        int kb = base_keep;
        for (int w = 0; w < wid; ++w) kb += wave_keep[w];
        if (keep) {
            int pos = kb + keep_before;
            top_idx[b * KTOP + pos] = n;
            unsigned fb = (u & 0x80000000u) ? (u & 0x7FFFFFFFu) : ~u;
            float f = __uint_as_float(fb);
            top_scores[b * KTOP + pos] = isinf(f) ? -1.0f : f;
        }
        for (int w = 0; w < 4; ++w) { base_eq += wave_eq[w]; base_keep += wave_keep[w]; }
        __syncthreads();
    }
}

// ---------------------------------------------------------------------------
// Kernel 7: final head (unchanged)
// ---------------------------------------------------------------------------
__global__ __launch_bounds__(256) void final_kernel(
    const float* __restrict__ AE,
    const int* __restrict__ s_idx, const int* __restrict__ e_idx,
    const int* __restrict__ maskp,
    const int* __restrict__ top_idx, const float* __restrict__ top_scores,
    const float* __restrict__ injv,
    const float* __restrict__ Wsec, const float* __restrict__ bsec,
    const float* __restrict__ Wpred, const float* __restrict__ bpredg,
    float* __restrict__ out)
{
    const int b = blockIdx.x >> 2;
    const int k0 = (blockIdx.x & 3) * 64;

    __shared__ float sh[64][36];
    __shared__ float Ws[32][260];
    __shared__ int ss[64], se[64];
    __shared__ float msk[64], tsc[64];

    const int t = threadIdx.x;
    if (t < 64) {
        int kidx = k0 + t;
        int n = top_idx[b * KTOP + kidx];
        int s = s_idx[n], e = e_idx[n];
        ss[t] = s; se[t] = e;
        msk[t] = (maskp[b * T + s] != 0 && maskp[b * T + e] != 0) ? 1.f : 0.f;
        tsc[t] = top_scores[b * KTOP + kidx];
    }
    __syncthreads();

    const int tx = t & 31;
    const int ty = t >> 5;
    float acc[8][8];
#pragma unroll
    for (int i = 0; i < 8; ++i)
#pragma unroll
        for (int j = 0; j < 8; ++j) acc[i][j] = 0.f;

    const float* Abase = AE + (size_t)b * T * 512;

    for (int kk = 0; kk < 256; kk += 32) {
        __syncthreads();
        {
            int c4 = (t & 63) * 4, r0 = t >> 6;
#pragma unroll
            for (int r8 = 0; r8 < 8; ++r8) {
                int row = r0 + r8 * 4;
                *(float4*)&Ws[row][c4] =
                    *(const float4*)&Wsec[(size_t)(kk + row) * 256 + c4];
            }
        }
        {
            int sp = t >> 2, k8 = (t & 3) * 8;
            const float* Ar = Abase + (size_t)ss[sp] * 512 + kk + k8;
            const float* Er = Abase + (size_t)se[sp] * 512 + 256 + kk + k8;
#pragma unroll
            for (int q = 0; q < 2; ++q) {
                float4 a = *(const float4*)&Ar[q * 4];
                float4 e = *(const float4*)&Er[q * 4];
                float4 v;
                v.x = a.x + e.x; v.y = a.y + e.y; v.z = a.z + e.z; v.w = a.w + e.w;
                *(float4*)&sh[sp][k8 + q * 4] = v;
            }
        }
        __syncthreads();
#pragma unroll
        for (int k4 = 0; k4 < 32; k4 += 4) {
            float w[4][8];
#pragma unroll
            for (int kq = 0; kq < 4; ++kq) {
                float4 w0 = *(const float4*)&Ws[k4 + kq][tx * 4];
                float4 w1 = *(const float4*)&Ws[k4 + kq][128 + tx * 4];
                w[kq][0] = w0.x; w[kq][1] = w0.y; w[kq][2] = w0.z; w[kq][3] = w0.w;
                w[kq][4] = w1.x; w[kq][5] = w1.y; w[kq][6] = w1.z; w[kq][7] = w1.w;
            }
#pragma unroll
            for (int i = 0; i < 8; ++i) {
                float4 rv = *(const float4*)&sh[ty * 8 + i][k4];
                float rq[4] = {rv.x, rv.y, rv.z, rv.w};
#pragma unroll
                for (int kq = 0; kq < 4; ++kq)
#pragma unroll
                    for (int j = 0; j < 8; ++j)
                        acc[i][j] = fmaf(rq[kq], w[kq][j], acc[i][j]);
            }
        }
    }

    float bsec_r[8], wpred_r[8], injr[8];
#pragma unroll
    for (int j = 0; j < 8; ++j) {
        int c = (j < 4) ? (tx * 4 + j) : (128 + tx * 4 + j - 4);
        bsec_r[j] = bsec[c];
        wpred_r[j] = Wpred[c];
        injr[j] = injv[b * H + c];
    }
    const float bp = bpredg[0];
#pragma unroll
    for (int i = 0; i < 8; ++i) {
        int r = ty * 8 + i;
        float p = 0.f;
#pragma unroll
        for (int j = 0; j < 8; ++j) {
            float sec = acc[i][j] + bsec_r[j];
            p += fmaxf(injr[j] + sec, 0.f) * wpred_r[j];
        }
#pragma unroll
        for (int off = 16; off > 0; off >>= 1)
            p += __shfl_down(p, off, 32);
        if (tx == 0) {
            float logit = p + bp + tsc[r];
            float prob = (1.f / (1.f + expf(-logit))) * msk[r];
            out[b * KTOP + k0 + r] = prob;
        }
    }
}

// ---------------------------------------------------------------------------
extern "C" void kernel_launch(void* const* d_in, const int* in_sizes, int n_in,
                              void* d_out, int out_size, void* d_ws, size_t ws_size,
                              hipStream_t stream) {
    const float* inputs  = (const float*)d_in[0];
    const int*   imask   = (const int*)d_in[1];
    const float* tie     = (const float*)d_in[2];
    const float* W_start = (const float*)d_in[3];
    const float* b_start = (const float*)d_in[4];
    const float* W_end   = (const float*)d_in[5];
    const float* b_end   = (const float*)d_in[6];
    const float* W_s1    = (const float*)d_in[7];
    const float* b_s1    = (const float*)d_in[8];
    const float* W_s2    = (const float*)d_in[9];
    const float* b_s2    = (const float*)d_in[10];
    const float* W_inj   = (const float*)d_in[11];
    const float* b_inj   = (const float*)d_in[12];
    const float* W_sec   = (const float*)d_in[13];
    const float* b_sec   = (const float*)d_in[14];
    const float* W_pred  = (const float*)d_in[15];
    const float* b_pred  = (const float*)d_in[16];
    float* out = (float*)d_out;

    float* AE         = (float*)d_ws;
    float* scores     = AE + (size_t)BB * T * 512;
    int*   s_idx      = (int*)(scores + (size_t)BB * NSPAN);
    int*   e_idx      = s_idx + NSPAN;
    int*   top_idx    = e_idx + NSPAN;
    float* top_scores = (float*)(top_idx + BB * KTOP);
    float* injv       = top_scores + BB * KTOP;
    unsigned short* Wpk = (unsigned short*)(injv + BB * H);
    int*   shortlist  = (int*)(Wpk + 65536);
    int*   slcnt      = shortlist + BB * SCAP;

    build_idx_kernel<<<1, 128, 0, stream>>>(s_idx, e_idx);
    proj_kernel<<<dim3(128, 4), 256, 0, stream>>>(inputs, W_start, b_start, W_end, b_end, AE);
    wpack_kernel<<<256, 256, 0, stream>>>(W_s1, Wpk);
    approx_kernel<<<dim3(65, BB), 256, 0, stream>>>(AE, Wpk, b_s1, W_s2, b_s2,
                                                    s_idx, e_idx, imask, scores);
    select_kernel<<<BB, 256, 0, stream>>>(scores, shortlist, slcnt);
    exact_kernel<<<dim3(16, BB), 256, 0, stream>>>(AE, W_s1, b_s1, W_s2, b_s2,
                                                   s_idx, e_idx, shortlist, slcnt, scores);
    inj_kernel<<<BB, 256, 0, stream>>>(tie, W_inj, b_inj, injv);
    topk_kernel<<<BB, 256, 0, stream>>>(scores, top_idx, top_scores);
    final_kernel<<<BB * 4, 256, 0, stream>>>(AE, s_idx, e_idx, imask, top_idx, top_scores,
                                             injv, W_sec, b_sec, W_pred, b_pred, out);
}